// Round 2
// baseline (6173.527 us; speedup 1.0000x reference)
//
#include <hip/hip_runtime.h>

// ======================================================================
// VQ-VAE forward, fp32 baseline. NHWC internal layout.
// B=32, CIN=3, IMG=128, D=256, K=512. Latent 32x32.
// Workspace budget: A0 (128MB) hosts transient latents A2/A3/A4 as
// aliases (A0 dead between conv2 and deconv1). Total ws = 178.6 MB.
// ======================================================================

// -------- weight permute: in[o*so + i*si + kh*sh + kw*sw] -> out[((kh*KW+kw)*I + i)*O + o]
__global__ void wt_perm_k(const float* __restrict__ in, float* __restrict__ out,
                          int O, int I, int KH, int KW,
                          int so, int si, int sh, int sw, int total)
{
    int idx = blockIdx.x * 256 + threadIdx.x;
    if (idx >= total) return;
    int o  = idx % O;
    int t  = idx / O;
    int i  = t % I;
    int t2 = t / I;
    int kw = t2 % KW;
    int kh = t2 / KW;
    out[idx] = in[o * so + i * si + kh * sh + kw * sw];
}

// -------- codebook row norms: nrm[k] = sum_c embed[k][c]^2
__global__ void norm_k(const float* __restrict__ e, float* __restrict__ nrm)
{
    int row = blockIdx.x;
    int lane = threadIdx.x;      // 64 threads
    float s = 0.f;
    #pragma unroll
    for (int c = 0; c < 256; c += 64) {
        float v = e[row * 256 + c + lane];
        s += v * v;
    }
    #pragma unroll
    for (int off = 1; off < 64; off <<= 1) s += __shfl_xor(s, off);
    if (lane == 0) nrm[row] = s;
}

__global__ void zero_k(float* p) { if (threadIdx.x == 0) p[0] = 0.f; }

__global__ void lossfin_k(const float* __restrict__ lacc, float* __restrict__ out)
{
    if (threadIdx.x == 0) {
        float m = lacc[0] * (1.0f / 32768.0f);
        out[1572864] = m;   // loss1
        out[1572865] = m;   // loss2 (same forward value; stop_gradient only affects grads)
    }
}

// ======================================================================
// conv1: x NCHW (B,3,128,128) -> out NHWC (B,64,64,256), k4 s2 p1, ReLU
// grid = B*64 (one output row), block 256 = 64 oc-lanes(x4 oc) * 4 ox-groups(16 ox)
// ======================================================================
__global__ void conv1_k(const float* __restrict__ x, const float* __restrict__ wt,
                        float* __restrict__ out)
{
    int bh = blockIdx.x;             // b*64 + oh
    int b = bh >> 6, oh = bh & 63;
    int lane_oc = (threadIdx.x & 63) << 2;
    int owg = threadIdx.x >> 6;
    int ow0 = owg << 4;
    __shared__ float lds[3][4][130]; // [c][kh-row][col(-1..128)]
    float acc[4][16] = {};
    for (int s = threadIdx.x; s < 3 * 4 * 130; s += 256) {
        int col = s % 130;
        int t = s / 130;
        int r = t & 3;
        int c = t >> 2;
        int ih = 2 * oh - 1 + r, iw = col - 1;
        float v = 0.f;
        if ((unsigned)ih < 128u && (unsigned)iw < 128u)
            v = x[(((b * 3 + c) << 7) + ih) * 128 + iw];
        lds[c][r][col] = v;
    }
    __syncthreads();
    for (int c = 0; c < 3; ++c) {
        #pragma unroll
        for (int kh = 0; kh < 4; ++kh) {
            float v[34];
            #pragma unroll
            for (int i = 0; i < 34; ++i) v[i] = lds[c][kh][(owg << 5) + i];
            #pragma unroll
            for (int kw = 0; kw < 4; ++kw) {
                const float4 w = *(const float4*)&wt[(((kh << 2) + kw) * 3 + c) * 256 + lane_oc];
                #pragma unroll
                for (int j = 0; j < 16; ++j) {
                    float xv = v[2 * j + kw];
                    acc[0][j] += w.x * xv;
                    acc[1][j] += w.y * xv;
                    acc[2][j] += w.z * xv;
                    acc[3][j] += w.w * xv;
                }
            }
        }
    }
    #pragma unroll
    for (int j = 0; j < 16; ++j) {
        int base = (((bh << 6) + ow0 + j) << 8) + lane_oc;
        float4 o;
        o.x = fmaxf(acc[0][j], 0.f);
        o.y = fmaxf(acc[1][j], 0.f);
        o.z = fmaxf(acc[2][j], 0.f);
        o.w = fmaxf(acc[3][j], 0.f);
        *(float4*)&out[base] = o;
    }
}

// ======================================================================
// conv2: NHWC (B,64,64,256) -> NHWC (B,32,32,256), k4 s2 p1, ReLU
// grid = B*32, block 256 = 64 oc-lanes(x4) * 4 ow-groups(8 ow)
// ======================================================================
__global__ void conv2_k(const float* __restrict__ in, const float* __restrict__ wt,
                        float* __restrict__ out)
{
    int bh = blockIdx.x;             // b*32 + oh
    int b = bh >> 5, oh = bh & 31;
    int lane_oc = (threadIdx.x & 63) << 2;
    int owg = threadIdx.x >> 6;
    int ow0 = owg << 3;
    __shared__ float lds[4][66][16]; // [kh-row][col(-1..64)][c-chunk]
    float acc[4][8] = {};
    for (int c0 = 0; c0 < 256; c0 += 16) {
        __syncthreads();
        for (int s = threadIdx.x; s < 4 * 66 * 16; s += 256) {
            int c = s & 15;
            int t = s >> 4;
            int col = t % 66;
            int r = t / 66;
            int ih = 2 * oh - 1 + r, iw = col - 1;
            float v = 0.f;
            if ((unsigned)ih < 64u && (unsigned)iw < 64u)
                v = in[((((b << 6) + ih) << 6) + iw) * 256 + c0 + c];
            lds[r][col][c] = v;
        }
        __syncthreads();
        for (int c = 0; c < 16; ++c) {
            #pragma unroll
            for (int kh = 0; kh < 4; ++kh) {
                float v[18];
                #pragma unroll
                for (int i = 0; i < 18; ++i) v[i] = lds[kh][(ow0 << 1) + i][c];
                #pragma unroll
                for (int kw = 0; kw < 4; ++kw) {
                    const float4 w = *(const float4*)&wt[((((kh << 2) + kw) << 8) + c0 + c) * 256 + lane_oc];
                    #pragma unroll
                    for (int j = 0; j < 8; ++j) {
                        float xv = v[2 * j + kw];
                        acc[0][j] += w.x * xv;
                        acc[1][j] += w.y * xv;
                        acc[2][j] += w.z * xv;
                        acc[3][j] += w.w * xv;
                    }
                }
            }
        }
    }
    #pragma unroll
    for (int j = 0; j < 8; ++j) {
        int base = (((bh << 5) + ow0 + j) << 8) + lane_oc;
        float4 o;
        o.x = fmaxf(acc[0][j], 0.f);
        o.y = fmaxf(acc[1][j], 0.f);
        o.z = fmaxf(acc[2][j], 0.f);
        o.w = fmaxf(acc[3][j], 0.f);
        *(float4*)&out[base] = o;
    }
}

// ======================================================================
// conv3x3 s1 p1, 256->256, 32x32, ReLU. grid = B*32
// ======================================================================
__global__ void conv3x3_relu_k(const float* __restrict__ in, const float* __restrict__ wt,
                               float* __restrict__ out)
{
    int bh = blockIdx.x;
    int b = bh >> 5, oh = bh & 31;
    int lane_oc = (threadIdx.x & 63) << 2;
    int owg = threadIdx.x >> 6;
    int ow0 = owg << 3;
    __shared__ float lds[3][34][32];
    float acc[4][8] = {};
    for (int c0 = 0; c0 < 256; c0 += 32) {
        __syncthreads();
        for (int s = threadIdx.x; s < 3 * 34 * 32; s += 256) {
            int c = s & 31;
            int t = s >> 5;
            int col = t % 34;
            int r = t / 34;
            int ih = oh - 1 + r, iw = col - 1;
            float v = 0.f;
            if ((unsigned)ih < 32u && (unsigned)iw < 32u)
                v = in[((((b << 5) + ih) << 5) + iw) * 256 + c0 + c];
            lds[r][col][c] = v;
        }
        __syncthreads();
        for (int c = 0; c < 32; ++c) {
            #pragma unroll
            for (int kh = 0; kh < 3; ++kh) {
                float v[10];
                #pragma unroll
                for (int i = 0; i < 10; ++i) v[i] = lds[kh][ow0 + i][c];
                #pragma unroll
                for (int kw = 0; kw < 3; ++kw) {
                    const float4 w = *(const float4*)&wt[(((kh * 3 + kw) << 8) + c0 + c) * 256 + lane_oc];
                    #pragma unroll
                    for (int j = 0; j < 8; ++j) {
                        float xv = v[j + kw];
                        acc[0][j] += w.x * xv;
                        acc[1][j] += w.y * xv;
                        acc[2][j] += w.z * xv;
                        acc[3][j] += w.w * xv;
                    }
                }
            }
        }
    }
    #pragma unroll
    for (int j = 0; j < 8; ++j) {
        int base = (((bh << 5) + ow0 + j) << 8) + lane_oc;
        float4 o;
        o.x = fmaxf(acc[0][j], 0.f);
        o.y = fmaxf(acc[1][j], 0.f);
        o.z = fmaxf(acc[2][j], 0.f);
        o.w = fmaxf(acc[3][j], 0.f);
        *(float4*)&out[base] = o;
    }
}

// ======================================================================
// conv1x1 + residual add (no relu), 256->256, 32x32. grid = B*32
// out = in @ W + res
// ======================================================================
__global__ void conv1x1_res_k(const float* __restrict__ in, const float* __restrict__ wt,
                              const float* __restrict__ res, float* __restrict__ out)
{
    int bh = blockIdx.x;
    int lane_oc = (threadIdx.x & 63) << 2;
    int owg = threadIdx.x >> 6;
    int ow0 = owg << 3;
    __shared__ float lds[32][64];
    float acc[4][8] = {};
    int rowbase = bh << 13;   // ((b*32+oh)*32)*256
    for (int c0 = 0; c0 < 256; c0 += 64) {
        __syncthreads();
        for (int s = threadIdx.x; s < 2048; s += 256) {
            int c = s & 63, ow = s >> 6;
            lds[ow][c] = in[rowbase + (ow << 8) + c0 + c];
        }
        __syncthreads();
        for (int c = 0; c < 64; ++c) {
            const float4 w = *(const float4*)&wt[(c0 + c) * 256 + lane_oc];
            #pragma unroll
            for (int j = 0; j < 8; ++j) {
                float v = lds[ow0 + j][c];
                acc[0][j] += w.x * v;
                acc[1][j] += w.y * v;
                acc[2][j] += w.z * v;
                acc[3][j] += w.w * v;
            }
        }
    }
    #pragma unroll
    for (int j = 0; j < 8; ++j) {
        int base = rowbase + ((ow0 + j) << 8) + lane_oc;
        float4 r = *(const float4*)&res[base];
        float4 o;
        o.x = acc[0][j] + r.x;
        o.y = acc[1][j] + r.y;
        o.z = acc[2][j] + r.z;
        o.w = acc[3][j] + r.w;
        *(float4*)&out[base] = o;
    }
}

// ======================================================================
// VQ: ze NHWC (B,32,32,256) -> zq (same layout) + loss accumulation
// grid = B*32 (32 pixels per block); block 256 = 64 k-lanes(x8 k) * 4 px-groups(8 px)
// ======================================================================
__global__ void vq_k(const float* __restrict__ ze, const float* __restrict__ embT,
                     const float* __restrict__ embed, const float* __restrict__ nrm,
                     float* __restrict__ zq, float* __restrict__ lacc)
{
    int bh = blockIdx.x;
    int klane = threadIdx.x & 63;
    int pxg = threadIdx.x >> 6;
    int px0 = pxg << 3;
    __shared__ float lds[32][64];
    float acc[8][8] = {};    // [px][k] dot(ze, e_k)
    int rowbase = bh << 13;
    for (int c0 = 0; c0 < 256; c0 += 64) {
        __syncthreads();
        for (int s = threadIdx.x; s < 2048; s += 256) {
            int c = s & 63, pw = s >> 6;
            lds[pw][c] = ze[rowbase + (pw << 8) + c0 + c];
        }
        __syncthreads();
        for (int c = 0; c < 64; ++c) {
            const float4 w0 = *(const float4*)&embT[(c0 + c) * 512 + (klane << 3)];
            const float4 w1 = *(const float4*)&embT[(c0 + c) * 512 + (klane << 3) + 4];
            #pragma unroll
            for (int j = 0; j < 8; ++j) {
                float v = lds[px0 + j][c];
                acc[j][0] += w0.x * v;
                acc[j][1] += w0.y * v;
                acc[j][2] += w0.z * v;
                acc[j][3] += w0.w * v;
                acc[j][4] += w1.x * v;
                acc[j][5] += w1.y * v;
                acc[j][6] += w1.z * v;
                acc[j][7] += w1.w * v;
            }
        }
    }
    float4 n0 = *(const float4*)&nrm[klane << 3];
    float4 n1 = *(const float4*)&nrm[(klane << 3) + 4];
    float nv[8] = {n0.x, n0.y, n0.z, n0.w, n1.x, n1.y, n1.z, n1.w};
    float lsum = 0.f;
    #pragma unroll
    for (int j = 0; j < 8; ++j) {
        // argmin_k ||ze - e_k||^2 == argmin_k (||e_k||^2 - 2 ze.e_k)
        float bv = 1e30f;
        int bi = 0x7fffffff;
        #pragma unroll
        for (int k = 0; k < 8; ++k) {
            float d = nv[k] - 2.f * acc[j][k];
            int ki = (klane << 3) + k;
            if (d < bv || (d == bv && ki < bi)) { bv = d; bi = ki; }
        }
        #pragma unroll
        for (int off = 1; off < 64; off <<= 1) {
            float ov = __shfl_xor(bv, off);
            int oi = __shfl_xor(bi, off);
            if (ov < bv || (ov == bv && oi < bi)) { bv = ov; bi = oi; }
        }
        // all 64 lanes agree on bi; copy code row + accumulate loss
        int pix = (bh << 5) + px0 + j;
        const float4 e = *(const float4*)&embed[bi * 256 + (klane << 2)];
        const float4 z = *(const float4*)&ze[(pix << 8) + (klane << 2)];
        *(float4*)&zq[(pix << 8) + (klane << 2)] = e;
        float dx = z.x - e.x, dy = z.y - e.y, dz = z.z - e.z, dw = z.w - e.w;
        lsum += dx * dx + dy * dy + dz * dz + dw * dw;
    }
    #pragma unroll
    for (int off = 1; off < 64; off <<= 1) lsum += __shfl_xor(lsum, off);
    if (klane == 0) atomicAdd(lacc, lsum);
}

// ======================================================================
// deconv1: ConvTranspose2d(256->256,k4,s2,p1)+bias+ReLU
// in NHWC (B,32,32,256) -> out NHWC (B,64,64,256). grid = B*64
// For output oy: kh in {p, p+2}, p=(oy+1)&1, ih=(oy+1-kh)/2 (zero if OOR)
// ======================================================================
__global__ void deconv1_k(const float* __restrict__ in, const float* __restrict__ wt,
                          const float* __restrict__ bias, float* __restrict__ out)
{
    int bo = blockIdx.x;             // b*64 + oy
    int b = bo >> 6, oy = bo & 63;
    int lane_oc = (threadIdx.x & 63) << 2;
    int oxg = threadIdx.x >> 6;
    int ox0 = oxg << 4;              // 16 ox per thread
    int p = (oy + 1) & 1;
    __shared__ float lds[2][34][32]; // [tap][col(-1..32)][c-chunk]
    float acc[4][16] = {};
    for (int c0 = 0; c0 < 256; c0 += 32) {
        __syncthreads();
        for (int s = threadIdx.x; s < 2 * 34 * 32; s += 256) {
            int c = s & 31;
            int t2 = s >> 5;
            int col = t2 % 34;
            int t = t2 / 34;
            int kh = p + 2 * t;
            int ih = (oy + 1 - kh) >> 1;
            int iw = col - 1;
            float v = 0.f;
            if ((unsigned)ih < 32u && (unsigned)iw < 32u)
                v = in[((((b << 5) + ih) << 5) + iw) * 256 + c0 + c];
            lds[t][col][c] = v;
        }
        __syncthreads();
        for (int c = 0; c < 32; ++c) {
            #pragma unroll
            for (int t = 0; t < 2; ++t) {
                int kh = p + 2 * t;
                float v[10];
                #pragma unroll
                for (int i = 0; i < 10; ++i) v[i] = lds[t][(oxg << 3) + i][c];
                #pragma unroll
                for (int kw = 0; kw < 4; ++kw) {
                    const float4 w = *(const float4*)&wt[((((kh << 2) + kw) << 8) + c0 + c) * 256 + lane_oc];
                    int j0 = (kw + 1) & 1;    // ox parity matching this kw
                    #pragma unroll
                    for (int jj = 0; jj < 8; ++jj) {
                        int j = 2 * jj + j0;
                        int i = ((j + 1 - kw) >> 1) + 1;
                        float xv = v[i];
                        acc[0][j] += w.x * xv;
                        acc[1][j] += w.y * xv;
                        acc[2][j] += w.z * xv;
                        acc[3][j] += w.w * xv;
                    }
                }
            }
        }
    }
    float4 bs = *(const float4*)&bias[lane_oc];
    #pragma unroll
    for (int j = 0; j < 16; ++j) {
        int base = (((bo << 6) + ox0 + j) << 8) + lane_oc;
        float4 o;
        o.x = fmaxf(acc[0][j] + bs.x, 0.f);
        o.y = fmaxf(acc[1][j] + bs.y, 0.f);
        o.z = fmaxf(acc[2][j] + bs.z, 0.f);
        o.w = fmaxf(acc[3][j] + bs.w, 0.f);
        *(float4*)&out[base] = o;
    }
}

// ======================================================================
// deconv2: ConvTranspose2d(256->3,k4,s2,p1)+bias+sigmoid
// in NHWC (B,64,64,256) -> out NCHW (B,3,128,128). grid = B*128
// block 256 = 128 ox * 2 cin-halves; halves reduced via LDS at the end
// ======================================================================
__global__ void deconv2_k(const float* __restrict__ in, const float* __restrict__ wt,
                          const float* __restrict__ bias, float* __restrict__ out)
{
    int bo = blockIdx.x;             // b*128 + oy
    int b = bo >> 7, oy = bo & 127;
    int ox = threadIdx.x & 127;
    int half = threadIdx.x >> 7;
    int p = (oy + 1) & 1;
    __shared__ float lds[2][66][33]; // [tap][col(-1..64)][c] (+1 pad to spread banks)
    __shared__ float red[128][3];
    float acc[3] = {0.f, 0.f, 0.f};
    int q = (ox + 1) & 1;
    for (int c0 = 0; c0 < 256; c0 += 32) {
        __syncthreads();
        for (int s = threadIdx.x; s < 2 * 66 * 32; s += 256) {
            int c = s & 31;
            int t2 = s >> 5;
            int col = t2 % 66;
            int t = t2 / 66;
            int kh = p + 2 * t;
            int ih = (oy + 1 - kh) >> 1;
            int iw = col - 1;
            float v = 0.f;
            if ((unsigned)ih < 64u && (unsigned)iw < 64u)
                v = in[((((b << 6) + ih) << 6) + iw) * 256 + c0 + c];
            lds[t][col][c] = v;
        }
        __syncthreads();
        for (int cc = 0; cc < 16; ++cc) {
            int c = (half << 4) + cc;
            #pragma unroll
            for (int t = 0; t < 2; ++t) {
                int kh = p + 2 * t;
                #pragma unroll
                for (int u = 0; u < 2; ++u) {
                    int kw = q + 2 * u;
                    int iw = (ox + 1 - kw) >> 1;
                    float v = lds[t][iw + 1][c];
                    const float* wp = &wt[((((kh << 2) + kw) << 8) + c0 + c) * 3];
                    acc[0] += wp[0] * v;
                    acc[1] += wp[1] * v;
                    acc[2] += wp[2] * v;
                }
            }
        }
    }
    if (half == 1) {
        red[ox][0] = acc[0];
        red[ox][1] = acc[1];
        red[ox][2] = acc[2];
    }
    __syncthreads();
    if (half == 0) {
        #pragma unroll
        for (int oc = 0; oc < 3; ++oc) {
            float r = acc[oc] + red[ox][oc] + bias[oc];
            r = 1.f / (1.f + expf(-r));
            out[(((b * 3 + oc) << 7) + oy) * 128 + ox] = r;
        }
    }
}

// ======================================================================
extern "C" void kernel_launch(void* const* d_in, const int* in_sizes, int n_in,
                              void* d_out, int out_size, void* d_ws, size_t ws_size,
                              hipStream_t stream)
{
    (void)in_sizes; (void)n_in; (void)out_size; (void)ws_size;
    const float* x      = (const float*)d_in[0];
    const float* embed  = (const float*)d_in[1];
    const float* e_w1   = (const float*)d_in[2];
    const float* e_w2   = (const float*)d_in[3];
    const float* e_r1a  = (const float*)d_in[4];
    const float* e_r1b  = (const float*)d_in[5];
    const float* e_r2a  = (const float*)d_in[6];
    const float* e_r2b  = (const float*)d_in[7];
    const float* d_r1a  = (const float*)d_in[8];
    const float* d_r1b  = (const float*)d_in[9];
    const float* d_r2a  = (const float*)d_in[10];
    const float* d_r2b  = (const float*)d_in[11];
    const float* dt1_w  = (const float*)d_in[12];
    const float* dt1_b  = (const float*)d_in[13];
    const float* dt2_w  = (const float*)d_in[14];
    const float* dt2_b  = (const float*)d_in[15];
    float* outp = (float*)d_out;

    // ---- workspace layout (floats). Total = 46,817,808 fl = 178.6 MB ----
    float* ws = (float*)d_ws;
    float* A0 = ws;                       // 33,554,432 fl: (B,64,64,256) h1 / up1
    // transient latents alias inside A0 (A0 dead between conv2 and deconv1):
    float* A2 = A0;                       // (B,32,32,256) = 8,388,608 fl
    float* A3 = A0 + 8388608;
    float* A4 = A0 + 16777216;
    float* A1 = ws + 33554432;            // 8,388,608 fl: persistent latent
    float* wp_ = ws + 41943040;           // weights region: 4,874,768 fl
    float* Wew1  = wp_; wp_ += 12288;
    float* Wew2  = wp_; wp_ += 1048576;
    float* Wer1a = wp_; wp_ += 589824;
    float* Wer1b = wp_; wp_ += 65536;
    float* Wer2a = wp_; wp_ += 589824;
    float* Wer2b = wp_; wp_ += 65536;
    float* Wdr1a = wp_; wp_ += 589824;
    float* Wdr1b = wp_; wp_ += 65536;
    float* Wdr2a = wp_; wp_ += 589824;
    float* Wdr2b = wp_; wp_ += 65536;
    float* Wdt1  = wp_; wp_ += 1048576;
    float* Wdt2  = wp_; wp_ += 12288;
    float* EmbT  = wp_; wp_ += 131072;    // (256,512) transposed codebook
    float* Nrm   = wp_; wp_ += 512;
    float* Lacc  = wp_; wp_ += 16;

    auto perm = [&](const float* i, float* o, int O, int I, int KH, int KW,
                    int so, int si, int sh, int sw) {
        int total = O * I * KH * KW;
        wt_perm_k<<<(total + 255) / 256, 256, 0, stream>>>(i, o, O, I, KH, KW, so, si, sh, sw, total);
    };
    // OIHW conv weights -> [kh][kw][ci][co]
    perm(e_w1, Wew1, 256, 3, 4, 4, 48, 16, 4, 1);
    perm(e_w2, Wew2, 256, 256, 4, 4, 4096, 16, 4, 1);
    perm(e_r1a, Wer1a, 256, 256, 3, 3, 2304, 9, 3, 1);
    perm(e_r1b, Wer1b, 256, 256, 1, 1, 256, 1, 1, 1);
    perm(e_r2a, Wer2a, 256, 256, 3, 3, 2304, 9, 3, 1);
    perm(e_r2b, Wer2b, 256, 256, 1, 1, 256, 1, 1, 1);
    perm(d_r1a, Wdr1a, 256, 256, 3, 3, 2304, 9, 3, 1);
    perm(d_r1b, Wdr1b, 256, 256, 1, 1, 256, 1, 1, 1);
    perm(d_r2a, Wdr2a, 256, 256, 3, 3, 2304, 9, 3, 1);
    perm(d_r2b, Wdr2b, 256, 256, 1, 1, 256, 1, 1, 1);
    // IOHW deconv weights (in,out,kh,kw) -> [kh][kw][ci][co]
    perm(dt1_w, Wdt1, 256, 256, 4, 4, 16, 4096, 4, 1);
    perm(dt2_w, Wdt2, 3, 256, 4, 4, 16, 48, 4, 1);
    // codebook transpose (K,D) -> (D,K)
    perm(embed, EmbT, 512, 256, 1, 1, 256, 1, 1, 1);
    norm_k<<<512, 64, 0, stream>>>(embed, Nrm);
    zero_k<<<1, 64, 0, stream>>>(Lacc);

    // ---- encoder ----
    conv1_k<<<32 * 64, 256, 0, stream>>>(x, Wew1, A0);
    conv2_k<<<32 * 32, 256, 0, stream>>>(A0, Wew2, A1);
    conv3x3_relu_k<<<32 * 32, 256, 0, stream>>>(A1, Wer1a, A2);
    conv1x1_res_k<<<32 * 32, 256, 0, stream>>>(A2, Wer1b, A1, A3);
    conv3x3_relu_k<<<32 * 32, 256, 0, stream>>>(A3, Wer2a, A2);
    conv1x1_res_k<<<32 * 32, 256, 0, stream>>>(A2, Wer2b, A3, A1);   // z_e in A1

    // ---- VQ ----
    vq_k<<<32 * 32, 256, 0, stream>>>(A1, EmbT, embed, Nrm, A3, Lacc); // z_q in A3

    // ---- decoder ----
    conv3x3_relu_k<<<32 * 32, 256, 0, stream>>>(A3, Wdr1a, A2);
    conv1x1_res_k<<<32 * 32, 256, 0, stream>>>(A2, Wdr1b, A3, A4);
    conv3x3_relu_k<<<32 * 32, 256, 0, stream>>>(A4, Wdr2a, A2);
    conv1x1_res_k<<<32 * 32, 256, 0, stream>>>(A2, Wdr2b, A4, A1);
    deconv1_k<<<32 * 64, 256, 0, stream>>>(A1, Wdt1, dt1_b, A0);
    deconv2_k<<<32 * 128, 256, 0, stream>>>(A0, Wdt2, dt2_b, outp);
    lossfin_k<<<1, 64, 0, stream>>>(Lacc, outp);
}

// Round 3
// 1522.693 us; speedup vs baseline: 4.0543x; 4.0543x over previous
//
#include <hip/hip_runtime.h>

// ======================================================================
// VQ-VAE forward. bf16 MFMA for all 256-ch convs; fp32 for conv1/deconv2/VQ.
// B=32, CIN=3, IMG=128, D=256, K=512. Latent 32x32. NHWC activations (bf16),
// channel dim padded to 264 in LDS (lane stride 132 dw == 4 mod 32: minimal
// bank aliasing for ds_read_b128). Weights pre-permuted to frag order
// Wf[khkw][cch][n][32] (wave reads 1KB contiguous, L2-resident).
// MFMA 16x16x32 bf16: A[m=lane&15][k=quad*8+j], B[n=lane&15][k=quad*8+j],
// D col=lane&15, row=quad*4+reg  (HW-verified mappings).
// ======================================================================

typedef __attribute__((ext_vector_type(8))) short bf16x8;
typedef __attribute__((ext_vector_type(4))) float f32x4;
#define MFMA_B16(a, b, c) __builtin_amdgcn_mfma_f32_16x16x32_bf16(a, b, c, 0, 0, 0)

__device__ inline unsigned short f2b(float f) {
    unsigned int u = __float_as_uint(f);
    unsigned int r = u + 0x7fffu + ((u >> 16) & 1u);
    return (unsigned short)(r >> 16);
}
__device__ inline float b2f(unsigned short u) {
    return __uint_as_float(((unsigned int)u) << 16);
}

// -------- fp32 weight permute (conv1, deconv2, EmbT): -> [((kh*KW+kw)*I + i)*O + o]
__global__ void wt_perm_k(const float* __restrict__ in, float* __restrict__ out,
                          int O, int I, int KH, int KW,
                          int so, int si, int sh, int sw, int total)
{
    int idx = blockIdx.x * 256 + threadIdx.x;
    if (idx >= total) return;
    int o  = idx % O;
    int t  = idx / O;
    int i  = t % I;
    int t2 = t / I;
    int kw = t2 % KW;
    int kh = t2 / KW;
    out[idx] = in[o * so + i * si + kh * sh + kw * sw];
}

// -------- bf16 frag-order weight permute:
// dst[(((kh*KW+kw)*CCH + cch)*256 + n)*32 + q] = bf16(src[n*s_o + (cch*32+q)*s_i + kh*s_h + kw*s_w])
__global__ void wt_permf_k(const float* __restrict__ src, unsigned short* __restrict__ dst,
                           int KW, int CCH, int s_o, int s_i, int s_h, int s_w, int total)
{
    int idx = blockIdx.x * 256 + threadIdx.x;
    if (idx >= total) return;
    int q = idx & 31;
    int n = (idx >> 5) & 255;
    int rest = idx >> 13;
    int cch = rest % CCH;
    int khkw = rest / CCH;
    int kh = khkw / KW, kw = khkw % KW;
    int ci = cch * 32 + q;
    dst[idx] = f2b(src[n * s_o + ci * s_i + kh * s_h + kw * s_w]);
}

// -------- codebook row norms
__global__ void norm_k(const float* __restrict__ e, float* __restrict__ nrm)
{
    int row = blockIdx.x;
    int lane = threadIdx.x;
    float s = 0.f;
    #pragma unroll
    for (int c = 0; c < 256; c += 64) {
        float v = e[row * 256 + c + lane];
        s += v * v;
    }
    #pragma unroll
    for (int off = 1; off < 64; off <<= 1) s += __shfl_xor(s, off);
    if (lane == 0) nrm[row] = s;
}

__global__ void zero_k(float* p) { if (threadIdx.x == 0) p[0] = 0.f; }

__global__ void lossfin_k(const float* __restrict__ lacc, float* __restrict__ out)
{
    if (threadIdx.x == 0) {
        float m = lacc[0] * (1.0f / 32768.0f);
        out[1572864] = m;
        out[1572865] = m;
    }
}

// ======================================================================
// conv1: x NCHW fp32 (B,3,128,128) -> NHWC bf16 (B,64,64,256), k4 s2 p1, ReLU
// ======================================================================
__global__ void conv1_k(const float* __restrict__ x, const float* __restrict__ wt,
                        unsigned short* __restrict__ out)
{
    int bh = blockIdx.x;             // b*64 + oh
    int b = bh >> 6, oh = bh & 63;
    int lane_oc = (threadIdx.x & 63) << 2;
    int owg = threadIdx.x >> 6;
    int ow0 = owg << 4;
    __shared__ float lds[3][4][130];
    float acc[4][16] = {};
    for (int s = threadIdx.x; s < 3 * 4 * 130; s += 256) {
        int col = s % 130;
        int t = s / 130;
        int r = t & 3;
        int c = t >> 2;
        int ih = 2 * oh - 1 + r, iw = col - 1;
        float v = 0.f;
        if ((unsigned)ih < 128u && (unsigned)iw < 128u)
            v = x[(((b * 3 + c) << 7) + ih) * 128 + iw];
        lds[c][r][col] = v;
    }
    __syncthreads();
    for (int c = 0; c < 3; ++c) {
        #pragma unroll
        for (int kh = 0; kh < 4; ++kh) {
            float v[34];
            #pragma unroll
            for (int i = 0; i < 34; ++i) v[i] = lds[c][kh][(owg << 5) + i];
            #pragma unroll
            for (int kw = 0; kw < 4; ++kw) {
                const float4 w = *(const float4*)&wt[(((kh << 2) + kw) * 3 + c) * 256 + lane_oc];
                #pragma unroll
                for (int j = 0; j < 16; ++j) {
                    float xv = v[2 * j + kw];
                    acc[0][j] += w.x * xv;
                    acc[1][j] += w.y * xv;
                    acc[2][j] += w.z * xv;
                    acc[3][j] += w.w * xv;
                }
            }
        }
    }
    #pragma unroll
    for (int j = 0; j < 16; ++j) {
        int base = (((bh << 6) + ow0 + j) << 8) + lane_oc;
        ushort4 o;
        o.x = f2b(fmaxf(acc[0][j], 0.f));
        o.y = f2b(fmaxf(acc[1][j], 0.f));
        o.z = f2b(fmaxf(acc[2][j], 0.f));
        o.w = f2b(fmaxf(acc[3][j], 0.f));
        *(ushort4*)&out[base] = o;
    }
}

// ======================================================================
// mconv2: bf16 MFMA, k4 s2 p1, in (B,64,64,256) -> out (B,32,32,256), ReLU
// grid = B*32 (one output row). Parity-split LDS columns for stride-2.
// ======================================================================
__global__ void __launch_bounds__(256, 4)
mconv2_k(const unsigned short* __restrict__ in, const unsigned short* __restrict__ wf,
         unsigned short* __restrict__ out)
{
    int bh = blockIdx.x;             // b*32 + oh
    int b = bh >> 5, oh = bh & 31;
    int lane = threadIdx.x & 63;
    int n0 = (threadIdx.x >> 6) << 6;
    int m = lane & 15;
    int quad = lane >> 4;
    __shared__ __align__(16) unsigned short win[66 * 264];
    f32x4 acc[2][4];
    f32x4 z = {0.f, 0.f, 0.f, 0.f};
    #pragma unroll
    for (int i = 0; i < 2; ++i)
        #pragma unroll
        for (int j = 0; j < 4; ++j) acc[i][j] = z;

    for (int kh = 0; kh < 4; ++kh) {
        int ih = 2 * oh - 1 + kh;
        __syncthreads();
        for (int s = threadIdx.x; s < 66 * 32; s += 256) {
            int c8 = s & 31, col = s >> 5;          // col = iw+1 in 0..65
            int iw = col - 1;
            int4 v = make_int4(0, 0, 0, 0);
            if ((unsigned)ih < 64u && (unsigned)iw < 64u)
                v = *(const int4*)&in[((((b << 6) + ih) << 6) + iw) * 256 + (c8 << 3)];
            int cs = (col >> 1) + (col & 1) * 33;   // parity-split
            *(int4*)&win[cs * 264 + (c8 << 3)] = v;
        }
        __syncthreads();
        for (int kw = 0; kw < 4; ++kw) {
            int csoff = (kw >> 1) + (kw & 1) * 33;
            #pragma unroll
            for (int cch = 0; cch < 8; ++cch) {
                bf16x8 a0 = *(const bf16x8*)&win[(m + csoff) * 264 + (cch << 5) + (quad << 3)];
                bf16x8 a1 = *(const bf16x8*)&win[(m + 16 + csoff) * 264 + (cch << 5) + (quad << 3)];
                int wbase = ((((kh << 2) + kw) * 8 + cch) * 256 + n0 + m) * 32 + (quad << 3);
                bf16x8 b0 = *(const bf16x8*)&wf[wbase];
                bf16x8 b1 = *(const bf16x8*)&wf[wbase + 16 * 32];
                bf16x8 b2 = *(const bf16x8*)&wf[wbase + 32 * 32];
                bf16x8 b3 = *(const bf16x8*)&wf[wbase + 48 * 32];
                acc[0][0] = MFMA_B16(a0, b0, acc[0][0]);
                acc[0][1] = MFMA_B16(a0, b1, acc[0][1]);
                acc[0][2] = MFMA_B16(a0, b2, acc[0][2]);
                acc[0][3] = MFMA_B16(a0, b3, acc[0][3]);
                acc[1][0] = MFMA_B16(a1, b0, acc[1][0]);
                acc[1][1] = MFMA_B16(a1, b1, acc[1][1]);
                acc[1][2] = MFMA_B16(a1, b2, acc[1][2]);
                acc[1][3] = MFMA_B16(a1, b3, acc[1][3]);
            }
        }
    }
    #pragma unroll
    for (int mt = 0; mt < 2; ++mt)
        #pragma unroll
        for (int nt = 0; nt < 4; ++nt)
            #pragma unroll
            for (int r = 0; r < 4; ++r) {
                int px = mt * 16 + quad * 4 + r;
                int col = n0 + nt * 16 + m;
                out[((bh << 5) + px) * 256 + col] = f2b(fmaxf(acc[mt][nt][r], 0.f));
            }
}

// ======================================================================
// mconv3: bf16 MFMA 3x3 s1 p1 + ReLU, (B,32,32,256)->(B,32,32,256). grid B*32
// ======================================================================
__global__ void __launch_bounds__(256, 4)
mconv3_k(const unsigned short* __restrict__ in, const unsigned short* __restrict__ wf,
         unsigned short* __restrict__ out)
{
    int bh = blockIdx.x;
    int b = bh >> 5, oh = bh & 31;
    int lane = threadIdx.x & 63;
    int n0 = (threadIdx.x >> 6) << 6;
    int m = lane & 15;
    int quad = lane >> 4;
    __shared__ __align__(16) unsigned short win[34 * 264];
    f32x4 acc[2][4];
    f32x4 z = {0.f, 0.f, 0.f, 0.f};
    #pragma unroll
    for (int i = 0; i < 2; ++i)
        #pragma unroll
        for (int j = 0; j < 4; ++j) acc[i][j] = z;

    for (int kh = 0; kh < 3; ++kh) {
        int ih = oh - 1 + kh;
        __syncthreads();
        for (int s = threadIdx.x; s < 34 * 32; s += 256) {
            int c8 = s & 31, col = s >> 5;          // col = iw+1 in 0..33
            int iw = col - 1;
            int4 v = make_int4(0, 0, 0, 0);
            if ((unsigned)ih < 32u && (unsigned)iw < 32u)
                v = *(const int4*)&in[((((b << 5) + ih) << 5) + iw) * 256 + (c8 << 3)];
            *(int4*)&win[col * 264 + (c8 << 3)] = v;
        }
        __syncthreads();
        for (int kw = 0; kw < 3; ++kw) {
            #pragma unroll
            for (int cch = 0; cch < 8; ++cch) {
                bf16x8 a0 = *(const bf16x8*)&win[(m + kw) * 264 + (cch << 5) + (quad << 3)];
                bf16x8 a1 = *(const bf16x8*)&win[(m + 16 + kw) * 264 + (cch << 5) + (quad << 3)];
                int wbase = (((kh * 3 + kw) * 8 + cch) * 256 + n0 + m) * 32 + (quad << 3);
                bf16x8 b0 = *(const bf16x8*)&wf[wbase];
                bf16x8 b1 = *(const bf16x8*)&wf[wbase + 16 * 32];
                bf16x8 b2 = *(const bf16x8*)&wf[wbase + 32 * 32];
                bf16x8 b3 = *(const bf16x8*)&wf[wbase + 48 * 32];
                acc[0][0] = MFMA_B16(a0, b0, acc[0][0]);
                acc[0][1] = MFMA_B16(a0, b1, acc[0][1]);
                acc[0][2] = MFMA_B16(a0, b2, acc[0][2]);
                acc[0][3] = MFMA_B16(a0, b3, acc[0][3]);
                acc[1][0] = MFMA_B16(a1, b0, acc[1][0]);
                acc[1][1] = MFMA_B16(a1, b1, acc[1][1]);
                acc[1][2] = MFMA_B16(a1, b2, acc[1][2]);
                acc[1][3] = MFMA_B16(a1, b3, acc[1][3]);
            }
        }
    }
    #pragma unroll
    for (int mt = 0; mt < 2; ++mt)
        #pragma unroll
        for (int nt = 0; nt < 4; ++nt)
            #pragma unroll
            for (int r = 0; r < 4; ++r) {
                int px = mt * 16 + quad * 4 + r;
                int col = n0 + nt * 16 + m;
                out[((bh << 5) + px) * 256 + col] = f2b(fmaxf(acc[mt][nt][r], 0.f));
            }
}

// ======================================================================
// m1x1: bf16 MFMA 1x1 + residual add. out bf16 and/or fp32 (f32out flag).
// grid B*32.
// ======================================================================
__global__ void __launch_bounds__(256, 4)
m1x1_k(const unsigned short* __restrict__ in, const unsigned short* __restrict__ wf,
       const unsigned short* __restrict__ res, unsigned short* __restrict__ outb,
       float* __restrict__ outf, int f32out)
{
    int bh = blockIdx.x;
    int lane = threadIdx.x & 63;
    int n0 = (threadIdx.x >> 6) << 6;
    int m = lane & 15;
    int quad = lane >> 4;
    __shared__ __align__(16) unsigned short win[32 * 264];
    f32x4 acc[2][4];
    f32x4 z = {0.f, 0.f, 0.f, 0.f};
    #pragma unroll
    for (int i = 0; i < 2; ++i)
        #pragma unroll
        for (int j = 0; j < 4; ++j) acc[i][j] = z;

    int rowbase = bh << 13;   // (bh*32)*256
    for (int s = threadIdx.x; s < 32 * 32; s += 256) {
        int c8 = s & 31, col = s >> 5;
        int4 v = *(const int4*)&in[rowbase + (col << 8) + (c8 << 3)];
        *(int4*)&win[col * 264 + (c8 << 3)] = v;
    }
    __syncthreads();
    #pragma unroll
    for (int cch = 0; cch < 8; ++cch) {
        bf16x8 a0 = *(const bf16x8*)&win[m * 264 + (cch << 5) + (quad << 3)];
        bf16x8 a1 = *(const bf16x8*)&win[(m + 16) * 264 + (cch << 5) + (quad << 3)];
        int wbase = (cch * 256 + n0 + m) * 32 + (quad << 3);
        bf16x8 b0 = *(const bf16x8*)&wf[wbase];
        bf16x8 b1 = *(const bf16x8*)&wf[wbase + 16 * 32];
        bf16x8 b2 = *(const bf16x8*)&wf[wbase + 32 * 32];
        bf16x8 b3 = *(const bf16x8*)&wf[wbase + 48 * 32];
        acc[0][0] = MFMA_B16(a0, b0, acc[0][0]);
        acc[0][1] = MFMA_B16(a0, b1, acc[0][1]);
        acc[0][2] = MFMA_B16(a0, b2, acc[0][2]);
        acc[0][3] = MFMA_B16(a0, b3, acc[0][3]);
        acc[1][0] = MFMA_B16(a1, b0, acc[1][0]);
        acc[1][1] = MFMA_B16(a1, b1, acc[1][1]);
        acc[1][2] = MFMA_B16(a1, b2, acc[1][2]);
        acc[1][3] = MFMA_B16(a1, b3, acc[1][3]);
    }
    #pragma unroll
    for (int mt = 0; mt < 2; ++mt)
        #pragma unroll
        for (int nt = 0; nt < 4; ++nt)
            #pragma unroll
            for (int r = 0; r < 4; ++r) {
                int px = mt * 16 + quad * 4 + r;
                int col = n0 + nt * 16 + m;
                int idx = rowbase + (px << 8) + col;
                float v = acc[mt][nt][r] + b2f(res[idx]);
                if (f32out) outf[idx] = v;
                else outb[idx] = f2b(v);
            }
}

// ======================================================================
// mdeconv1: bf16 MFMA ConvTranspose2d(256->256,k4,s2,p1)+bias+ReLU
// in (B,32,32,256) -> out (B,64,64,256). grid = B*64 (one oy row).
// oy parity p: kh in {p,p+2}, ih = r0 - t. ox parity par: kw in {q,q+2}, q=1-par.
// ======================================================================
__global__ void __launch_bounds__(256, 4)
mdeconv1_k(const unsigned short* __restrict__ in, const unsigned short* __restrict__ wf,
           const float* __restrict__ bias, unsigned short* __restrict__ out)
{
    int bo = blockIdx.x;             // b*64 + oy
    int b = bo >> 6, oy = bo & 63;
    int p = (oy + 1) & 1;
    int r0 = (oy + 1 - p) >> 1;
    int lane = threadIdx.x & 63;
    int n0 = (threadIdx.x >> 6) << 6;
    int m = lane & 15;
    int quad = lane >> 4;
    __shared__ __align__(16) unsigned short win[2 * 34 * 264];

    for (int s = threadIdx.x; s < 2 * 34 * 32; s += 256) {
        int c8 = s & 31;
        int t2 = s >> 5;
        int col = t2 % 34;           // col = iw+1 in 0..33
        int t = t2 / 34;
        int ih = r0 - t, iw = col - 1;
        int4 v = make_int4(0, 0, 0, 0);
        if ((unsigned)ih < 32u && (unsigned)iw < 32u)
            v = *(const int4*)&in[((((b << 5) + ih) << 5) + iw) * 256 + (c8 << 3)];
        *(int4*)&win[(t * 34 + col) * 264 + (c8 << 3)] = v;
    }
    __syncthreads();

    for (int par = 0; par < 2; ++par) {
        int q = 1 - par;
        int shift = (par + 1 - q) >> 1;      // 0 (par0) or 1 (par1)
        f32x4 acc[2][4];
        f32x4 z = {0.f, 0.f, 0.f, 0.f};
        #pragma unroll
        for (int i = 0; i < 2; ++i)
            #pragma unroll
            for (int j = 0; j < 4; ++j) acc[i][j] = z;

        for (int t = 0; t < 2; ++t) {
            int kh = p + 2 * t;
            for (int u = 0; u < 2; ++u) {
                int kw = q + 2 * u;
                int ixoff = shift - u + 1;   // col index offset for lane m
                #pragma unroll
                for (int cch = 0; cch < 8; ++cch) {
                    bf16x8 a0 = *(const bf16x8*)&win[(t * 34 + m + ixoff) * 264 + (cch << 5) + (quad << 3)];
                    bf16x8 a1 = *(const bf16x8*)&win[(t * 34 + m + 16 + ixoff) * 264 + (cch << 5) + (quad << 3)];
                    int wbase = ((((kh << 2) + kw) * 8 + cch) * 256 + n0 + m) * 32 + (quad << 3);
                    bf16x8 b0 = *(const bf16x8*)&wf[wbase];
                    bf16x8 b1 = *(const bf16x8*)&wf[wbase + 16 * 32];
                    bf16x8 b2 = *(const bf16x8*)&wf[wbase + 32 * 32];
                    bf16x8 b3 = *(const bf16x8*)&wf[wbase + 48 * 32];
                    acc[0][0] = MFMA_B16(a0, b0, acc[0][0]);
                    acc[0][1] = MFMA_B16(a0, b1, acc[0][1]);
                    acc[0][2] = MFMA_B16(a0, b2, acc[0][2]);
                    acc[0][3] = MFMA_B16(a0, b3, acc[0][3]);
                    acc[1][0] = MFMA_B16(a1, b0, acc[1][0]);
                    acc[1][1] = MFMA_B16(a1, b1, acc[1][1]);
                    acc[1][2] = MFMA_B16(a1, b2, acc[1][2]);
                    acc[1][3] = MFMA_B16(a1, b3, acc[1][3]);
                }
            }
        }
        #pragma unroll
        for (int mt = 0; mt < 2; ++mt)
            #pragma unroll
            for (int nt = 0; nt < 4; ++nt)
                #pragma unroll
                for (int r = 0; r < 4; ++r) {
                    int midx = mt * 16 + quad * 4 + r;
                    int ox = 2 * midx + par;
                    int col = n0 + nt * 16 + m;
                    float v = fmaxf(acc[mt][nt][r] + bias[col], 0.f);
                    out[(((bo << 6) + ox) << 8) + col] = f2b(v);
                }
    }
}

// ======================================================================
// VQ: ze fp32 NHWC -> zq bf16 + fp32 loss. grid = B*32.
// ======================================================================
__global__ void vq_k(const float* __restrict__ ze, const float* __restrict__ embT,
                     const float* __restrict__ embed, const float* __restrict__ nrm,
                     unsigned short* __restrict__ zq, float* __restrict__ lacc)
{
    int bh = blockIdx.x;
    int klane = threadIdx.x & 63;
    int pxg = threadIdx.x >> 6;
    int px0 = pxg << 3;
    __shared__ float lds[32][64];
    float acc[8][8] = {};
    int rowbase = bh << 13;
    for (int c0 = 0; c0 < 256; c0 += 64) {
        __syncthreads();
        for (int s = threadIdx.x; s < 2048; s += 256) {
            int c = s & 63, pw = s >> 6;
            lds[pw][c] = ze[rowbase + (pw << 8) + c0 + c];
        }
        __syncthreads();
        for (int c = 0; c < 64; ++c) {
            const float4 w0 = *(const float4*)&embT[(c0 + c) * 512 + (klane << 3)];
            const float4 w1 = *(const float4*)&embT[(c0 + c) * 512 + (klane << 3) + 4];
            #pragma unroll
            for (int j = 0; j < 8; ++j) {
                float v = lds[px0 + j][c];
                acc[j][0] += w0.x * v;
                acc[j][1] += w0.y * v;
                acc[j][2] += w0.z * v;
                acc[j][3] += w0.w * v;
                acc[j][4] += w1.x * v;
                acc[j][5] += w1.y * v;
                acc[j][6] += w1.z * v;
                acc[j][7] += w1.w * v;
            }
        }
    }
    float4 n0 = *(const float4*)&nrm[klane << 3];
    float4 n1 = *(const float4*)&nrm[(klane << 3) + 4];
    float nv[8] = {n0.x, n0.y, n0.z, n0.w, n1.x, n1.y, n1.z, n1.w};
    float lsum = 0.f;
    #pragma unroll
    for (int j = 0; j < 8; ++j) {
        float bv = 1e30f;
        int bi = 0x7fffffff;
        #pragma unroll
        for (int k = 0; k < 8; ++k) {
            float d = nv[k] - 2.f * acc[j][k];
            int ki = (klane << 3) + k;
            if (d < bv || (d == bv && ki < bi)) { bv = d; bi = ki; }
        }
        #pragma unroll
        for (int off = 1; off < 64; off <<= 1) {
            float ov = __shfl_xor(bv, off);
            int oi = __shfl_xor(bi, off);
            if (ov < bv || (ov == bv && oi < bi)) { bv = ov; bi = oi; }
        }
        int pix = (bh << 5) + px0 + j;
        const float4 e = *(const float4*)&embed[bi * 256 + (klane << 2)];
        const float4 zv = *(const float4*)&ze[(pix << 8) + (klane << 2)];
        ushort4 eq;
        eq.x = f2b(e.x); eq.y = f2b(e.y); eq.z = f2b(e.z); eq.w = f2b(e.w);
        *(ushort4*)&zq[(pix << 8) + (klane << 2)] = eq;
        float dx = zv.x - e.x, dy = zv.y - e.y, dz = zv.z - e.z, dw = zv.w - e.w;
        lsum += dx * dx + dy * dy + dz * dz + dw * dw;
    }
    #pragma unroll
    for (int off = 1; off < 64; off <<= 1) lsum += __shfl_xor(lsum, off);
    if (klane == 0) atomicAdd(lacc, lsum);
}

// ======================================================================
// deconv2: ConvTranspose2d(256->3,k4,s2,p1)+bias+sigmoid
// in bf16 (B,64,64,256) -> out fp32 NCHW (B,3,128,128). grid = B*128
// ======================================================================
__global__ void deconv2_k(const unsigned short* __restrict__ in, const float* __restrict__ wt,
                          const float* __restrict__ bias, float* __restrict__ out)
{
    int bo = blockIdx.x;
    int b = bo >> 7, oy = bo & 127;
    int ox = threadIdx.x & 127;
    int half = threadIdx.x >> 7;
    int p = (oy + 1) & 1;
    __shared__ float lds[2][66][33];
    __shared__ float red[128][3];
    float acc[3] = {0.f, 0.f, 0.f};
    int q = (ox + 1) & 1;
    for (int c0 = 0; c0 < 256; c0 += 32) {
        __syncthreads();
        for (int s = threadIdx.x; s < 2 * 66 * 32; s += 256) {
            int c = s & 31;
            int t2 = s >> 5;
            int col = t2 % 66;
            int t = t2 / 66;
            int kh = p + 2 * t;
            int ih = (oy + 1 - kh) >> 1;
            int iw = col - 1;
            float v = 0.f;
            if ((unsigned)ih < 64u && (unsigned)iw < 64u)
                v = b2f(in[((((b << 6) + ih) << 6) + iw) * 256 + c0 + c]);
            lds[t][col][c] = v;
        }
        __syncthreads();
        for (int cc = 0; cc < 16; ++cc) {
            int c = (half << 4) + cc;
            #pragma unroll
            for (int t = 0; t < 2; ++t) {
                int kh = p + 2 * t;
                #pragma unroll
                for (int u = 0; u < 2; ++u) {
                    int kw = q + 2 * u;
                    int iw = (ox + 1 - kw) >> 1;
                    float v = lds[t][iw + 1][c];
                    const float* wp = &wt[((((kh << 2) + kw) << 8) + c0 + c) * 3];
                    acc[0] += wp[0] * v;
                    acc[1] += wp[1] * v;
                    acc[2] += wp[2] * v;
                }
            }
        }
    }
    if (half == 1) {
        red[ox][0] = acc[0];
        red[ox][1] = acc[1];
        red[ox][2] = acc[2];
    }
    __syncthreads();
    if (half == 0) {
        #pragma unroll
        for (int oc = 0; oc < 3; ++oc) {
            float r = acc[oc] + red[ox][oc] + bias[oc];
            r = 1.f / (1.f + expf(-r));
            out[(((b * 3 + oc) << 7) + oy) * 128 + ox] = r;
        }
    }
}

// ======================================================================
extern "C" void kernel_launch(void* const* d_in, const int* in_sizes, int n_in,
                              void* d_out, int out_size, void* d_ws, size_t ws_size,
                              hipStream_t stream)
{
    (void)in_sizes; (void)n_in; (void)out_size; (void)ws_size;
    const float* x      = (const float*)d_in[0];
    const float* embed  = (const float*)d_in[1];
    const float* e_w1   = (const float*)d_in[2];
    const float* e_w2   = (const float*)d_in[3];
    const float* e_r1a  = (const float*)d_in[4];
    const float* e_r1b  = (const float*)d_in[5];
    const float* e_r2a  = (const float*)d_in[6];
    const float* e_r2b  = (const float*)d_in[7];
    const float* d_r1a  = (const float*)d_in[8];
    const float* d_r1b  = (const float*)d_in[9];
    const float* d_r2a  = (const float*)d_in[10];
    const float* d_r2b  = (const float*)d_in[11];
    const float* dt1_w  = (const float*)d_in[12];
    const float* dt1_b  = (const float*)d_in[13];
    const float* dt2_w  = (const float*)d_in[14];
    const float* dt2_b  = (const float*)d_in[15];
    float* outp = (float*)d_out;

    // ---- workspace layout (bytes) ----
    char* base = (char*)d_ws;
    size_t off = 0;
    auto alloc = [&](size_t bytes) { char* p = base + off; off += (bytes + 255) & ~size_t(255); return p; };
    unsigned short* A0b = (unsigned short*)alloc(67108864);  // (B,64,64,256) bf16
    float*          A1f = (float*)alloc(33554432);           // ze fp32
    unsigned short* L0  = (unsigned short*)alloc(16777216);  // latent bf16
    unsigned short* L1  = (unsigned short*)alloc(16777216);
    unsigned short* L2  = (unsigned short*)alloc(16777216);
    unsigned short* Wf_ew2  = (unsigned short*)alloc(2097152);
    unsigned short* Wf_er1a = (unsigned short*)alloc(1179648);
    unsigned short* Wf_er1b = (unsigned short*)alloc(131072);
    unsigned short* Wf_er2a = (unsigned short*)alloc(1179648);
    unsigned short* Wf_er2b = (unsigned short*)alloc(131072);
    unsigned short* Wf_dr1a = (unsigned short*)alloc(1179648);
    unsigned short* Wf_dr1b = (unsigned short*)alloc(131072);
    unsigned short* Wf_dr2a = (unsigned short*)alloc(1179648);
    unsigned short* Wf_dr2b = (unsigned short*)alloc(131072);
    unsigned short* Wf_dt1  = (unsigned short*)alloc(2097152);
    float* Wew1 = (float*)alloc(49152);
    float* Wdt2 = (float*)alloc(49152);
    float* EmbT = (float*)alloc(524288);
    float* Nrm  = (float*)alloc(2048);
    float* Lacc = (float*)alloc(64);

    auto permf = [&](const float* s, unsigned short* d, int KH, int KW,
                     int s_o, int s_i, int s_h, int s_w) {
        int total = KH * KW * 8 * 256 * 32;
        wt_permf_k<<<(total + 255) / 256, 256, 0, stream>>>(s, d, KW, 8, s_o, s_i, s_h, s_w, total);
    };
    // conv OIHW -> frag layout
    permf(e_w2,  Wf_ew2,  4, 4, 4096, 16, 4, 1);
    permf(e_r1a, Wf_er1a, 3, 3, 2304, 9, 3, 1);
    permf(e_r1b, Wf_er1b, 1, 1, 256, 1, 0, 0);
    permf(e_r2a, Wf_er2a, 3, 3, 2304, 9, 3, 1);
    permf(e_r2b, Wf_er2b, 1, 1, 256, 1, 0, 0);
    permf(d_r1a, Wf_dr1a, 3, 3, 2304, 9, 3, 1);
    permf(d_r1b, Wf_dr1b, 1, 1, 256, 1, 0, 0);
    permf(d_r2a, Wf_dr2a, 3, 3, 2304, 9, 3, 1);
    permf(d_r2b, Wf_dr2b, 1, 1, 256, 1, 0, 0);
    // deconv1 IOHW: element(kh,kw,ci,n) = dt1_w[ci*4096 + n*16 + kh*4 + kw]
    permf(dt1_w, Wf_dt1, 4, 4, 16, 4096, 4, 1);
    // fp32 perms: conv1 weights, deconv2 weights, codebook transpose
    wt_perm_k<<<(12288 + 255) / 256, 256, 0, stream>>>(e_w1, Wew1, 256, 3, 4, 4, 48, 16, 4, 1, 12288);
    wt_perm_k<<<(12288 + 255) / 256, 256, 0, stream>>>(dt2_w, Wdt2, 3, 256, 4, 4, 16, 48, 4, 1, 12288);
    wt_perm_k<<<(131072 + 255) / 256, 256, 0, stream>>>(embed, EmbT, 512, 256, 1, 1, 256, 1, 1, 1, 131072);
    norm_k<<<512, 64, 0, stream>>>(embed, Nrm);
    zero_k<<<1, 64, 0, stream>>>(Lacc);

    // ---- encoder ----
    conv1_k<<<32 * 64, 256, 0, stream>>>(x, Wew1, A0b);
    mconv2_k<<<32 * 32, 256, 0, stream>>>(A0b, Wf_ew2, L1);             // h
    mconv3_k<<<32 * 32, 256, 0, stream>>>(L1, Wf_er1a, L2);
    m1x1_k<<<32 * 32, 256, 0, stream>>>(L2, Wf_er1b, L1, L0, nullptr, 0);   // r1 -> L0
    mconv3_k<<<32 * 32, 256, 0, stream>>>(L0, Wf_er2a, L2);
    m1x1_k<<<32 * 32, 256, 0, stream>>>(L2, Wf_er2b, L0, nullptr, A1f, 1);  // ze (fp32) -> A1f

    // ---- VQ ----
    vq_k<<<32 * 32, 256, 0, stream>>>(A1f, EmbT, embed, Nrm, L1, Lacc); // zq (bf16) -> L1

    // ---- decoder ----
    mconv3_k<<<32 * 32, 256, 0, stream>>>(L1, Wf_dr1a, L2);
    m1x1_k<<<32 * 32, 256, 0, stream>>>(L2, Wf_dr1b, L1, L0, nullptr, 0);   // d1 -> L0
    mconv3_k<<<32 * 32, 256, 0, stream>>>(L0, Wf_dr2a, L2);
    m1x1_k<<<32 * 32, 256, 0, stream>>>(L2, Wf_dr2b, L0, L1, nullptr, 0);   // d2 -> L1
    mdeconv1_k<<<32 * 64, 256, 0, stream>>>(L1, Wf_dt1, dt1_b, A0b);
    deconv2_k<<<32 * 128, 256, 0, stream>>>(A0b, Wdt2, dt2_b, outp);
    lossfin_k<<<1, 64, 0, stream>>>(Lacc, outp);
}

// Round 4
// 1090.604 us; speedup vs baseline: 5.6606x; 1.3962x over previous
//
#include <hip/hip_runtime.h>

// ======================================================================
// VQ-VAE forward. bf16 MFMA for all GEMM-shaped work (256-ch convs, VQ
// distance GEMM, deconv2 tap-GEMM); fp32 for conv1 + exact VQ loss path.
// B=32, CIN=3, IMG=128, D=256, K=512. Latent 32x32. NHWC bf16 activations,
// LDS channel stride 264 (bank-friendly for ds_read_b128). Weights
// frag-ordered: Wf[khkw][cch][n][32]. MFMA 16x16x32 bf16 mappings:
// A[m=lane&15][k=quad*8+j], B[n=lane&15][k=quad*8+j], D col=lane&15,
// row=quad*4+reg (HW-verified).
// ======================================================================

typedef __attribute__((ext_vector_type(8))) short bf16x8;
typedef __attribute__((ext_vector_type(4))) float f32x4;
#define MFMA_B16(a, b, c) __builtin_amdgcn_mfma_f32_16x16x32_bf16(a, b, c, 0, 0, 0)

__device__ inline unsigned short f2b(float f) {
    unsigned int u = __float_as_uint(f);
    unsigned int r = u + 0x7fffu + ((u >> 16) & 1u);
    return (unsigned short)(r >> 16);
}
__device__ inline float b2f(unsigned short u) {
    return __uint_as_float(((unsigned int)u) << 16);
}

// -------- fp32 weight permute (conv1): -> [((kh*KW+kw)*I + i)*O + o]
__global__ void wt_perm_k(const float* __restrict__ in, float* __restrict__ out,
                          int O, int I, int KH, int KW,
                          int so, int si, int sh, int sw, int total)
{
    int idx = blockIdx.x * 256 + threadIdx.x;
    if (idx >= total) return;
    int o  = idx % O;
    int t  = idx / O;
    int i  = t % I;
    int t2 = t / I;
    int kw = t2 % KW;
    int kh = t2 / KW;
    out[idx] = in[o * so + i * si + kh * sh + kw * sw];
}

// -------- bf16 frag-order weight permute (N=256):
// dst[(((kh*KW+kw)*8 + cch)*256 + n)*32 + q] = bf16(src[n*s_o + (cch*32+q)*s_i + kh*s_h + kw*s_w])
__global__ void wt_permf_k(const float* __restrict__ src, unsigned short* __restrict__ dst,
                           int KW, int s_o, int s_i, int s_h, int s_w, int total)
{
    int idx = blockIdx.x * 256 + threadIdx.x;
    if (idx >= total) return;
    int q = idx & 31;
    int n = (idx >> 5) & 255;
    int rest = idx >> 13;
    int cch = rest & 7;
    int khkw = rest >> 3;
    int kh = khkw / KW, kw = khkw % KW;
    int ci = cch * 32 + q;
    dst[idx] = f2b(src[n * s_o + ci * s_i + kh * s_h + kw * s_w]);
}

// -------- deconv2 weight -> frag order (N=48): n = (kh*4+kw)*3 + oc
// dst[(cch*48 + n)*32 + q] = bf16(dt2_w[(cch*32+q)*48 + oc*16 + kh*4 + kw])
__global__ void dec2w_k(const float* __restrict__ src, unsigned short* __restrict__ dst)
{
    int idx = blockIdx.x * 256 + threadIdx.x;
    if (idx >= 12288) return;
    int q = idx & 31;
    int n = (idx >> 5) % 48;
    int cch = idx / (48 * 32);
    int ci = cch * 32 + q;
    int oc = n % 3, khkw = n / 3;
    int kh = khkw >> 2, kw = khkw & 3;
    dst[idx] = f2b(src[ci * 48 + oc * 16 + kh * 4 + kw]);
}

// -------- codebook -> frag order bf16: dst[(cch*512 + n)*32 + q] = bf16(embed[n*256 + cch*32 + q])
__global__ void embf_k(const float* __restrict__ e, unsigned short* __restrict__ dst)
{
    int idx = blockIdx.x * 256 + threadIdx.x;   // 131072
    int q = idx & 31;
    int n = (idx >> 5) & 511;
    int cch = idx >> 14;
    dst[idx] = f2b(e[n * 256 + cch * 32 + q]);
}

// -------- codebook row norms (fp32 exact)
__global__ void norm_k(const float* __restrict__ e, float* __restrict__ nrm)
{
    int row = blockIdx.x;
    int lane = threadIdx.x;
    float s = 0.f;
    #pragma unroll
    for (int c = 0; c < 256; c += 64) {
        float v = e[row * 256 + c + lane];
        s += v * v;
    }
    #pragma unroll
    for (int off = 1; off < 64; off <<= 1) s += __shfl_xor(s, off);
    if (lane == 0) nrm[row] = s;
}

__global__ void zero_k(float* p) { if (threadIdx.x == 0) p[0] = 0.f; }

__global__ void lossfin_k(const float* __restrict__ lacc, float* __restrict__ out)
{
    if (threadIdx.x == 0) {
        float m = lacc[0] * (1.0f / 32768.0f);
        out[1572864] = m;
        out[1572865] = m;
    }
}

// ======================================================================
// conv1: x NCHW fp32 (B,3,128,128) -> NHWC bf16 (B,64,64,256), k4 s2 p1, ReLU
// ======================================================================
__global__ void conv1_k(const float* __restrict__ x, const float* __restrict__ wt,
                        unsigned short* __restrict__ out)
{
    int bh = blockIdx.x;             // b*64 + oh
    int b = bh >> 6, oh = bh & 63;
    int lane_oc = (threadIdx.x & 63) << 2;
    int owg = threadIdx.x >> 6;
    int ow0 = owg << 4;
    __shared__ float lds[3][4][130];
    float acc[4][16] = {};
    for (int s = threadIdx.x; s < 3 * 4 * 130; s += 256) {
        int col = s % 130;
        int t = s / 130;
        int r = t & 3;
        int c = t >> 2;
        int ih = 2 * oh - 1 + r, iw = col - 1;
        float v = 0.f;
        if ((unsigned)ih < 128u && (unsigned)iw < 128u)
            v = x[(((b * 3 + c) << 7) + ih) * 128 + iw];
        lds[c][r][col] = v;
    }
    __syncthreads();
    for (int c = 0; c < 3; ++c) {
        #pragma unroll
        for (int kh = 0; kh < 4; ++kh) {
            float v[34];
            #pragma unroll
            for (int i = 0; i < 34; ++i) v[i] = lds[c][kh][(owg << 5) + i];
            #pragma unroll
            for (int kw = 0; kw < 4; ++kw) {
                const float4 w = *(const float4*)&wt[(((kh << 2) + kw) * 3 + c) * 256 + lane_oc];
                #pragma unroll
                for (int j = 0; j < 16; ++j) {
                    float xv = v[2 * j + kw];
                    acc[0][j] += w.x * xv;
                    acc[1][j] += w.y * xv;
                    acc[2][j] += w.z * xv;
                    acc[3][j] += w.w * xv;
                }
            }
        }
    }
    #pragma unroll
    for (int j = 0; j < 16; ++j) {
        int base = (((bh << 6) + ow0 + j) << 8) + lane_oc;
        ushort4 o;
        o.x = f2b(fmaxf(acc[0][j], 0.f));
        o.y = f2b(fmaxf(acc[1][j], 0.f));
        o.z = f2b(fmaxf(acc[2][j], 0.f));
        o.w = f2b(fmaxf(acc[3][j], 0.f));
        *(ushort4*)&out[base] = o;
    }
}

// ======================================================================
// mconv2: bf16 MFMA, k4 s2 p1, (B,64,64,256)->(B,32,32,256), ReLU. grid B*32
// ======================================================================
__global__ void __launch_bounds__(256, 4)
mconv2_k(const unsigned short* __restrict__ in, const unsigned short* __restrict__ wf,
         unsigned short* __restrict__ out)
{
    int bh = blockIdx.x;             // b*32 + oh
    int b = bh >> 5, oh = bh & 31;
    int lane = threadIdx.x & 63;
    int n0 = (threadIdx.x >> 6) << 6;
    int m = lane & 15;
    int quad = lane >> 4;
    __shared__ __align__(16) unsigned short win[66 * 264];
    f32x4 acc[2][4];
    f32x4 z = {0.f, 0.f, 0.f, 0.f};
    #pragma unroll
    for (int i = 0; i < 2; ++i)
        #pragma unroll
        for (int j = 0; j < 4; ++j) acc[i][j] = z;

    for (int kh = 0; kh < 4; ++kh) {
        int ih = 2 * oh - 1 + kh;
        __syncthreads();
        for (int s = threadIdx.x; s < 66 * 32; s += 256) {
            int c8 = s & 31, col = s >> 5;          // col = iw+1 in 0..65
            int iw = col - 1;
            int4 v = make_int4(0, 0, 0, 0);
            if ((unsigned)ih < 64u && (unsigned)iw < 64u)
                v = *(const int4*)&in[((((b << 6) + ih) << 6) + iw) * 256 + (c8 << 3)];
            int cs = (col >> 1) + (col & 1) * 33;   // parity-split
            *(int4*)&win[cs * 264 + (c8 << 3)] = v;
        }
        __syncthreads();
        for (int kw = 0; kw < 4; ++kw) {
            int csoff = (kw >> 1) + (kw & 1) * 33;
            #pragma unroll
            for (int cch = 0; cch < 8; ++cch) {
                bf16x8 a0 = *(const bf16x8*)&win[(m + csoff) * 264 + (cch << 5) + (quad << 3)];
                bf16x8 a1 = *(const bf16x8*)&win[(m + 16 + csoff) * 264 + (cch << 5) + (quad << 3)];
                int wbase = ((((kh << 2) + kw) * 8 + cch) * 256 + n0 + m) * 32 + (quad << 3);
                bf16x8 b0 = *(const bf16x8*)&wf[wbase];
                bf16x8 b1 = *(const bf16x8*)&wf[wbase + 16 * 32];
                bf16x8 b2 = *(const bf16x8*)&wf[wbase + 32 * 32];
                bf16x8 b3 = *(const bf16x8*)&wf[wbase + 48 * 32];
                acc[0][0] = MFMA_B16(a0, b0, acc[0][0]);
                acc[0][1] = MFMA_B16(a0, b1, acc[0][1]);
                acc[0][2] = MFMA_B16(a0, b2, acc[0][2]);
                acc[0][3] = MFMA_B16(a0, b3, acc[0][3]);
                acc[1][0] = MFMA_B16(a1, b0, acc[1][0]);
                acc[1][1] = MFMA_B16(a1, b1, acc[1][1]);
                acc[1][2] = MFMA_B16(a1, b2, acc[1][2]);
                acc[1][3] = MFMA_B16(a1, b3, acc[1][3]);
            }
        }
    }
    #pragma unroll
    for (int mt = 0; mt < 2; ++mt)
        #pragma unroll
        for (int nt = 0; nt < 4; ++nt)
            #pragma unroll
            for (int r = 0; r < 4; ++r) {
                int px = mt * 16 + quad * 4 + r;
                int col = n0 + nt * 16 + m;
                out[((bh << 5) + px) * 256 + col] = f2b(fmaxf(acc[mt][nt][r], 0.f));
            }
}

// ======================================================================
// mconv3: bf16 MFMA 3x3 s1 p1 + ReLU, (B,32,32,256)->(B,32,32,256). grid B*32
// ======================================================================
__global__ void __launch_bounds__(256, 4)
mconv3_k(const unsigned short* __restrict__ in, const unsigned short* __restrict__ wf,
         unsigned short* __restrict__ out)
{
    int bh = blockIdx.x;
    int b = bh >> 5, oh = bh & 31;
    int lane = threadIdx.x & 63;
    int n0 = (threadIdx.x >> 6) << 6;
    int m = lane & 15;
    int quad = lane >> 4;
    __shared__ __align__(16) unsigned short win[34 * 264];
    f32x4 acc[2][4];
    f32x4 z = {0.f, 0.f, 0.f, 0.f};
    #pragma unroll
    for (int i = 0; i < 2; ++i)
        #pragma unroll
        for (int j = 0; j < 4; ++j) acc[i][j] = z;

    for (int kh = 0; kh < 3; ++kh) {
        int ih = oh - 1 + kh;
        __syncthreads();
        for (int s = threadIdx.x; s < 34 * 32; s += 256) {
            int c8 = s & 31, col = s >> 5;          // col = iw+1 in 0..33
            int iw = col - 1;
            int4 v = make_int4(0, 0, 0, 0);
            if ((unsigned)ih < 32u && (unsigned)iw < 32u)
                v = *(const int4*)&in[((((b << 5) + ih) << 5) + iw) * 256 + (c8 << 3)];
            *(int4*)&win[col * 264 + (c8 << 3)] = v;
        }
        __syncthreads();
        for (int kw = 0; kw < 3; ++kw) {
            #pragma unroll
            for (int cch = 0; cch < 8; ++cch) {
                bf16x8 a0 = *(const bf16x8*)&win[(m + kw) * 264 + (cch << 5) + (quad << 3)];
                bf16x8 a1 = *(const bf16x8*)&win[(m + 16 + kw) * 264 + (cch << 5) + (quad << 3)];
                int wbase = (((kh * 3 + kw) * 8 + cch) * 256 + n0 + m) * 32 + (quad << 3);
                bf16x8 b0 = *(const bf16x8*)&wf[wbase];
                bf16x8 b1 = *(const bf16x8*)&wf[wbase + 16 * 32];
                bf16x8 b2 = *(const bf16x8*)&wf[wbase + 32 * 32];
                bf16x8 b3 = *(const bf16x8*)&wf[wbase + 48 * 32];
                acc[0][0] = MFMA_B16(a0, b0, acc[0][0]);
                acc[0][1] = MFMA_B16(a0, b1, acc[0][1]);
                acc[0][2] = MFMA_B16(a0, b2, acc[0][2]);
                acc[0][3] = MFMA_B16(a0, b3, acc[0][3]);
                acc[1][0] = MFMA_B16(a1, b0, acc[1][0]);
                acc[1][1] = MFMA_B16(a1, b1, acc[1][1]);
                acc[1][2] = MFMA_B16(a1, b2, acc[1][2]);
                acc[1][3] = MFMA_B16(a1, b3, acc[1][3]);
            }
        }
    }
    #pragma unroll
    for (int mt = 0; mt < 2; ++mt)
        #pragma unroll
        for (int nt = 0; nt < 4; ++nt)
            #pragma unroll
            for (int r = 0; r < 4; ++r) {
                int px = mt * 16 + quad * 4 + r;
                int col = n0 + nt * 16 + m;
                out[((bh << 5) + px) * 256 + col] = f2b(fmaxf(acc[mt][nt][r], 0.f));
            }
}

// ======================================================================
// m1x1: bf16 MFMA 1x1 + residual add. Always writes bf16 outb; also fp32
// outf when f32out (dual output for the ze -> VQ exact-loss path). grid B*32.
// ======================================================================
__global__ void __launch_bounds__(256, 4)
m1x1_k(const unsigned short* __restrict__ in, const unsigned short* __restrict__ wf,
       const unsigned short* __restrict__ res, unsigned short* __restrict__ outb,
       float* __restrict__ outf, int f32out)
{
    int bh = blockIdx.x;
    int lane = threadIdx.x & 63;
    int n0 = (threadIdx.x >> 6) << 6;
    int m = lane & 15;
    int quad = lane >> 4;
    __shared__ __align__(16) unsigned short win[32 * 264];
    f32x4 acc[2][4];
    f32x4 z = {0.f, 0.f, 0.f, 0.f};
    #pragma unroll
    for (int i = 0; i < 2; ++i)
        #pragma unroll
        for (int j = 0; j < 4; ++j) acc[i][j] = z;

    int rowbase = bh << 13;   // (bh*32)*256
    for (int s = threadIdx.x; s < 32 * 32; s += 256) {
        int c8 = s & 31, col = s >> 5;
        int4 v = *(const int4*)&in[rowbase + (col << 8) + (c8 << 3)];
        *(int4*)&win[col * 264 + (c8 << 3)] = v;
    }
    __syncthreads();
    #pragma unroll
    for (int cch = 0; cch < 8; ++cch) {
        bf16x8 a0 = *(const bf16x8*)&win[m * 264 + (cch << 5) + (quad << 3)];
        bf16x8 a1 = *(const bf16x8*)&win[(m + 16) * 264 + (cch << 5) + (quad << 3)];
        int wbase = (cch * 256 + n0 + m) * 32 + (quad << 3);
        bf16x8 b0 = *(const bf16x8*)&wf[wbase];
        bf16x8 b1 = *(const bf16x8*)&wf[wbase + 16 * 32];
        bf16x8 b2 = *(const bf16x8*)&wf[wbase + 32 * 32];
        bf16x8 b3 = *(const bf16x8*)&wf[wbase + 48 * 32];
        acc[0][0] = MFMA_B16(a0, b0, acc[0][0]);
        acc[0][1] = MFMA_B16(a0, b1, acc[0][1]);
        acc[0][2] = MFMA_B16(a0, b2, acc[0][2]);
        acc[0][3] = MFMA_B16(a0, b3, acc[0][3]);
        acc[1][0] = MFMA_B16(a1, b0, acc[1][0]);
        acc[1][1] = MFMA_B16(a1, b1, acc[1][1]);
        acc[1][2] = MFMA_B16(a1, b2, acc[1][2]);
        acc[1][3] = MFMA_B16(a1, b3, acc[1][3]);
    }
    #pragma unroll
    for (int mt = 0; mt < 2; ++mt)
        #pragma unroll
        for (int nt = 0; nt < 4; ++nt)
            #pragma unroll
            for (int r = 0; r < 4; ++r) {
                int px = mt * 16 + quad * 4 + r;
                int col = n0 + nt * 16 + m;
                int idx = rowbase + (px << 8) + col;
                float v = acc[mt][nt][r] + b2f(res[idx]);
                outb[idx] = f2b(v);
                if (f32out) outf[idx] = v;
            }
}

// ======================================================================
// mdeconv1: bf16 MFMA ConvTranspose2d(256->256,k4,s2,p1)+bias+ReLU
// (B,32,32,256) -> (B,64,64,256). grid = B*64 (one oy row).
// ======================================================================
__global__ void __launch_bounds__(256, 4)
mdeconv1_k(const unsigned short* __restrict__ in, const unsigned short* __restrict__ wf,
           const float* __restrict__ bias, unsigned short* __restrict__ out)
{
    int bo = blockIdx.x;             // b*64 + oy
    int b = bo >> 6, oy = bo & 63;
    int p = (oy + 1) & 1;
    int r0 = (oy + 1 - p) >> 1;
    int lane = threadIdx.x & 63;
    int n0 = (threadIdx.x >> 6) << 6;
    int m = lane & 15;
    int quad = lane >> 4;
    __shared__ __align__(16) unsigned short win[2 * 34 * 264];

    for (int s = threadIdx.x; s < 2 * 34 * 32; s += 256) {
        int c8 = s & 31;
        int t2 = s >> 5;
        int col = t2 % 34;           // col = iw+1 in 0..33
        int t = t2 / 34;
        int ih = r0 - t, iw = col - 1;
        int4 v = make_int4(0, 0, 0, 0);
        if ((unsigned)ih < 32u && (unsigned)iw < 32u)
            v = *(const int4*)&in[((((b << 5) + ih) << 5) + iw) * 256 + (c8 << 3)];
        *(int4*)&win[(t * 34 + col) * 264 + (c8 << 3)] = v;
    }
    __syncthreads();

    for (int par = 0; par < 2; ++par) {
        int q = 1 - par;
        int shift = (par + 1 - q) >> 1;
        f32x4 acc[2][4];
        f32x4 z = {0.f, 0.f, 0.f, 0.f};
        #pragma unroll
        for (int i = 0; i < 2; ++i)
            #pragma unroll
            for (int j = 0; j < 4; ++j) acc[i][j] = z;

        for (int t = 0; t < 2; ++t) {
            int kh = p + 2 * t;
            for (int u = 0; u < 2; ++u) {
                int kw = q + 2 * u;
                int ixoff = shift - u + 1;
                #pragma unroll
                for (int cch = 0; cch < 8; ++cch) {
                    bf16x8 a0 = *(const bf16x8*)&win[(t * 34 + m + ixoff) * 264 + (cch << 5) + (quad << 3)];
                    bf16x8 a1 = *(const bf16x8*)&win[(t * 34 + m + 16 + ixoff) * 264 + (cch << 5) + (quad << 3)];
                    int wbase = ((((kh << 2) + kw) * 8 + cch) * 256 + n0 + m) * 32 + (quad << 3);
                    bf16x8 b0 = *(const bf16x8*)&wf[wbase];
                    bf16x8 b1 = *(const bf16x8*)&wf[wbase + 16 * 32];
                    bf16x8 b2 = *(const bf16x8*)&wf[wbase + 32 * 32];
                    bf16x8 b3 = *(const bf16x8*)&wf[wbase + 48 * 32];
                    acc[0][0] = MFMA_B16(a0, b0, acc[0][0]);
                    acc[0][1] = MFMA_B16(a0, b1, acc[0][1]);
                    acc[0][2] = MFMA_B16(a0, b2, acc[0][2]);
                    acc[0][3] = MFMA_B16(a0, b3, acc[0][3]);
                    acc[1][0] = MFMA_B16(a1, b0, acc[1][0]);
                    acc[1][1] = MFMA_B16(a1, b1, acc[1][1]);
                    acc[1][2] = MFMA_B16(a1, b2, acc[1][2]);
                    acc[1][3] = MFMA_B16(a1, b3, acc[1][3]);
                }
            }
        }
        #pragma unroll
        for (int mt = 0; mt < 2; ++mt)
            #pragma unroll
            for (int nt = 0; nt < 4; ++nt)
                #pragma unroll
                for (int r = 0; r < 4; ++r) {
                    int midx = mt * 16 + quad * 4 + r;
                    int ox = 2 * midx + par;
                    int col = n0 + nt * 16 + m;
                    float v = fmaxf(acc[mt][nt][r] + bias[col], 0.f);
                    out[(((bo << 6) + ox) << 8) + col] = f2b(v);
                }
    }
}

// ======================================================================
// vqm: MFMA VQ. GEMM ze(bf16) x codebook^T via mfma; argmin in fp32 margins;
// zq gather + loss in exact fp32. grid = B*32 (32 px/block).
// Wave w covers codewords [w*128, w*128+128).
// ======================================================================
__global__ void __launch_bounds__(256, 2)
vqm_k(const unsigned short* __restrict__ zeb, const float* __restrict__ zef,
      const unsigned short* __restrict__ embF, const float* __restrict__ embed,
      const float* __restrict__ nrm, unsigned short* __restrict__ zq,
      float* __restrict__ lacc)
{
    int bh = blockIdx.x;
    int tid = threadIdx.x;
    int lane = tid & 63;
    int wv = tid >> 6;
    int m = lane & 15, quad = lane >> 4;
    __shared__ __align__(16) unsigned short win[32 * 264];
    __shared__ float bvv[4][32];
    __shared__ int   bii[4][32];
    __shared__ int   bidx[32];
    int rowbase = bh << 13;
    for (int s = tid; s < 32 * 32; s += 256) {
        int c8 = s & 31, px = s >> 5;
        *(int4*)&win[px * 264 + (c8 << 3)] = *(const int4*)&zeb[rowbase + (px << 8) + (c8 << 3)];
    }
    __syncthreads();

    f32x4 acc[2][8];
    f32x4 z = {0.f, 0.f, 0.f, 0.f};
    #pragma unroll
    for (int i = 0; i < 2; ++i)
        #pragma unroll
        for (int j = 0; j < 8; ++j) acc[i][j] = z;

    #pragma unroll
    for (int cch = 0; cch < 8; ++cch) {
        bf16x8 a0 = *(const bf16x8*)&win[m * 264 + (cch << 5) + (quad << 3)];
        bf16x8 a1 = *(const bf16x8*)&win[(m + 16) * 264 + (cch << 5) + (quad << 3)];
        #pragma unroll
        for (int nt = 0; nt < 8; ++nt) {
            bf16x8 b = *(const bf16x8*)&embF[((cch << 9) + (wv << 7) + (nt << 4) + m) * 32 + (quad << 3)];
            acc[0][nt] = MFMA_B16(a0, b, acc[0][nt]);
            acc[1][nt] = MFMA_B16(a1, b, acc[1][nt]);
        }
    }

    float nv[8];
    #pragma unroll
    for (int nt = 0; nt < 8; ++nt) nv[nt] = nrm[(wv << 7) + (nt << 4) + m];

    #pragma unroll
    for (int mt = 0; mt < 2; ++mt)
        #pragma unroll
        for (int r = 0; r < 4; ++r) {
            float bv = 1e30f;
            int bi = 0x7fffffff;
            #pragma unroll
            for (int nt = 0; nt < 8; ++nt) {
                float d = nv[nt] - 2.f * acc[mt][nt][r];
                int n = (wv << 7) + (nt << 4) + m;
                if (d < bv || (d == bv && n < bi)) { bv = d; bi = n; }
            }
            #pragma unroll
            for (int off = 1; off < 16; off <<= 1) {   // stays within quad
                float ov = __shfl_xor(bv, off);
                int oi = __shfl_xor(bi, off);
                if (ov < bv || (ov == bv && oi < bi)) { bv = ov; bi = oi; }
            }
            if (m == 0) {
                int px = mt * 16 + quad * 4 + r;
                bvv[wv][px] = bv;
                bii[wv][px] = bi;
            }
        }
    __syncthreads();
    if (tid < 32) {
        float bv = bvv[0][tid];
        int bi = bii[0][tid];
        #pragma unroll
        for (int w2 = 1; w2 < 4; ++w2) {
            float ov = bvv[w2][tid];
            int oi = bii[w2][tid];
            if (ov < bv || (ov == bv && oi < bi)) { bv = ov; bi = oi; }
        }
        bidx[tid] = bi;
    }
    __syncthreads();

    // exact-fp32 gather + loss: group wv handles 8 px
    float lsum = 0.f;
    #pragma unroll
    for (int j = 0; j < 8; ++j) {
        int px = (wv << 3) + j;
        int bi = bidx[px];
        int pix = (bh << 5) + px;
        const float4 e = *(const float4*)&embed[bi * 256 + (lane << 2)];
        const float4 zv = *(const float4*)&zef[(pix << 8) + (lane << 2)];
        ushort4 eq;
        eq.x = f2b(e.x); eq.y = f2b(e.y); eq.z = f2b(e.z); eq.w = f2b(e.w);
        *(ushort4*)&zq[(pix << 8) + (lane << 2)] = eq;
        float dx = zv.x - e.x, dy = zv.y - e.y, dz = zv.z - e.z, dw = zv.w - e.w;
        lsum += dx * dx + dy * dy + dz * dz + dw * dw;
    }
    #pragma unroll
    for (int off = 1; off < 64; off <<= 1) lsum += __shfl_xor(lsum, off);
    if (lane == 0) atomicAdd(lacc, lsum);
}

// ======================================================================
// mdec2a: deconv2 pass 1 — GEMM Y[B*64*64, 48] = X[.,256] x Wg[256,48]
// n = (kh*4+kw)*3 + oc. grid = 2048 blocks x 64 px.
// ======================================================================
__global__ void __launch_bounds__(256, 4)
mdec2a_k(const unsigned short* __restrict__ in, const unsigned short* __restrict__ wg,
         float* __restrict__ Y)
{
    int tid = threadIdx.x;
    int lane = tid & 63;
    int wv = tid >> 6;
    int m = lane & 15, quad = lane >> 4;
    __shared__ __align__(16) unsigned short win[64 * 264];
    int pxbase = blockIdx.x << 6;
    for (int s = tid; s < 64 * 32; s += 256) {
        int c8 = s & 31, px = s >> 5;
        *(int4*)&win[px * 264 + (c8 << 3)] = *(const int4*)&in[((pxbase + px) << 8) + (c8 << 3)];
    }
    __syncthreads();
    f32x4 acc[3];
    f32x4 z = {0.f, 0.f, 0.f, 0.f};
    acc[0] = z; acc[1] = z; acc[2] = z;
    #pragma unroll
    for (int cch = 0; cch < 8; ++cch) {
        bf16x8 a = *(const bf16x8*)&win[((wv << 4) + m) * 264 + (cch << 5) + (quad << 3)];
        #pragma unroll
        for (int nt = 0; nt < 3; ++nt) {
            bf16x8 b = *(const bf16x8*)&wg[(cch * 48 + nt * 16 + m) * 32 + (quad << 3)];
            acc[nt] = MFMA_B16(a, b, acc[nt]);
        }
    }
    #pragma unroll
    for (int nt = 0; nt < 3; ++nt)
        #pragma unroll
        for (int r = 0; r < 4; ++r) {
            int px = pxbase + (wv << 4) + quad * 4 + r;
            Y[px * 48 + nt * 16 + m] = acc[nt][r];
        }
}

// ======================================================================
// dec2b: deconv2 pass 2 — gather <=4 taps from Y, +bias, sigmoid, NCHW out.
// one thread per output pixel. grid = 2048 x 256.
// ======================================================================
__global__ void dec2b_k(const float* __restrict__ Y, const float* __restrict__ bias,
                        float* __restrict__ out)
{
    int idx = blockIdx.x * 256 + threadIdx.x;    // < 524288
    int b = idx >> 14;
    int rem = idx & 16383;
    int oy = rem >> 7;
    int ox = rem & 127;
    int p = (oy + 1) & 1;
    int q = (ox + 1) & 1;
    float acc0 = bias[0], acc1 = bias[1], acc2 = bias[2];
    #pragma unroll
    for (int t = 0; t < 2; ++t) {
        int kh = p + 2 * t;
        int ih = (oy + 1 - kh) >> 1;
        if ((unsigned)ih >= 64u) continue;
        #pragma unroll
        for (int u = 0; u < 2; ++u) {
            int kw = q + 2 * u;
            int iw = (ox + 1 - kw) >> 1;
            if ((unsigned)iw >= 64u) continue;
            int base = ((((b << 6) + ih) << 6) + iw) * 48 + ((kh << 2) + kw) * 3;
            acc0 += Y[base];
            acc1 += Y[base + 1];
            acc2 += Y[base + 2];
        }
    }
    int obase = (b * 3 << 14) + (oy << 7) + ox;
    out[obase]           = 1.f / (1.f + expf(-acc0));
    out[obase + 16384]   = 1.f / (1.f + expf(-acc1));
    out[obase + 32768]   = 1.f / (1.f + expf(-acc2));
}

// ======================================================================
extern "C" void kernel_launch(void* const* d_in, const int* in_sizes, int n_in,
                              void* d_out, int out_size, void* d_ws, size_t ws_size,
                              hipStream_t stream)
{
    (void)in_sizes; (void)n_in; (void)out_size; (void)ws_size;
    const float* x      = (const float*)d_in[0];
    const float* embed  = (const float*)d_in[1];
    const float* e_w1   = (const float*)d_in[2];
    const float* e_w2   = (const float*)d_in[3];
    const float* e_r1a  = (const float*)d_in[4];
    const float* e_r1b  = (const float*)d_in[5];
    const float* e_r2a  = (const float*)d_in[6];
    const float* e_r2b  = (const float*)d_in[7];
    const float* d_r1a  = (const float*)d_in[8];
    const float* d_r1b  = (const float*)d_in[9];
    const float* d_r2a  = (const float*)d_in[10];
    const float* d_r2b  = (const float*)d_in[11];
    const float* dt1_w  = (const float*)d_in[12];
    const float* dt1_b  = (const float*)d_in[13];
    const float* dt2_w  = (const float*)d_in[14];
    const float* dt2_b  = (const float*)d_in[15];
    float* outp = (float*)d_out;

    // ---- workspace layout ----
    char* base = (char*)d_ws;
    size_t off = 0;
    auto alloc = [&](size_t bytes) { char* p = base + off; off += (bytes + 255) & ~size_t(255); return p; };
    unsigned short* A0b = (unsigned short*)alloc(67108864);  // (B,64,64,256) bf16
    float*          A1f = (float*)alloc(33554432);           // ze fp32; later Y (25MB)
    unsigned short* L0  = (unsigned short*)alloc(16777216);
    unsigned short* L1  = (unsigned short*)alloc(16777216);
    unsigned short* L2  = (unsigned short*)alloc(16777216);
    unsigned short* Wf_ew2  = (unsigned short*)alloc(2097152);
    unsigned short* Wf_er1a = (unsigned short*)alloc(1179648);
    unsigned short* Wf_er1b = (unsigned short*)alloc(131072);
    unsigned short* Wf_er2a = (unsigned short*)alloc(1179648);
    unsigned short* Wf_er2b = (unsigned short*)alloc(131072);
    unsigned short* Wf_dr1a = (unsigned short*)alloc(1179648);
    unsigned short* Wf_dr1b = (unsigned short*)alloc(131072);
    unsigned short* Wf_dr2a = (unsigned short*)alloc(1179648);
    unsigned short* Wf_dr2b = (unsigned short*)alloc(131072);
    unsigned short* Wf_dt1  = (unsigned short*)alloc(2097152);
    unsigned short* Wg      = (unsigned short*)alloc(24576);   // deconv2 frag weights
    unsigned short* EmbF    = (unsigned short*)alloc(262144);  // codebook frag bf16
    float* Wew1 = (float*)alloc(49152);
    float* Nrm  = (float*)alloc(2048);
    float* Lacc = (float*)alloc(64);
    float* Y = A1f;   // alias: A1f (ze) dead after vqm_k

    auto permf = [&](const float* s, unsigned short* d, int KH, int KW,
                     int s_o, int s_i, int s_h, int s_w) {
        int total = KH * KW * 8 * 256 * 32;
        wt_permf_k<<<(total + 255) / 256, 256, 0, stream>>>(s, d, KW, s_o, s_i, s_h, s_w, total);
    };
    permf(e_w2,  Wf_ew2,  4, 4, 4096, 16, 4, 1);
    permf(e_r1a, Wf_er1a, 3, 3, 2304, 9, 3, 1);
    permf(e_r1b, Wf_er1b, 1, 1, 256, 1, 0, 0);
    permf(e_r2a, Wf_er2a, 3, 3, 2304, 9, 3, 1);
    permf(e_r2b, Wf_er2b, 1, 1, 256, 1, 0, 0);
    permf(d_r1a, Wf_dr1a, 3, 3, 2304, 9, 3, 1);
    permf(d_r1b, Wf_dr1b, 1, 1, 256, 1, 0, 0);
    permf(d_r2a, Wf_dr2a, 3, 3, 2304, 9, 3, 1);
    permf(d_r2b, Wf_dr2b, 1, 1, 256, 1, 0, 0);
    permf(dt1_w, Wf_dt1, 4, 4, 16, 4096, 4, 1);
    dec2w_k<<<48, 256, 0, stream>>>(dt2_w, Wg);
    embf_k<<<512, 256, 0, stream>>>(embed, EmbF);
    wt_perm_k<<<48, 256, 0, stream>>>(e_w1, Wew1, 256, 3, 4, 4, 48, 16, 4, 1, 12288);
    norm_k<<<512, 64, 0, stream>>>(embed, Nrm);
    zero_k<<<1, 64, 0, stream>>>(Lacc);

    // ---- encoder ----
    conv1_k<<<32 * 64, 256, 0, stream>>>(x, Wew1, A0b);
    mconv2_k<<<32 * 32, 256, 0, stream>>>(A0b, Wf_ew2, L1);                  // h
    mconv3_k<<<32 * 32, 256, 0, stream>>>(L1, Wf_er1a, L2);
    m1x1_k<<<32 * 32, 256, 0, stream>>>(L2, Wf_er1b, L1, L0, nullptr, 0);    // r1 -> L0 (L1 dead)
    mconv3_k<<<32 * 32, 256, 0, stream>>>(L0, Wf_er2a, L2);
    m1x1_k<<<32 * 32, 256, 0, stream>>>(L2, Wf_er2b, L0, L1, A1f, 1);        // ze: bf16->L1, fp32->A1f

    // ---- VQ (reads ze bf16 from L1 + fp32 from A1f; writes zq bf16 to L1 in-place per-row) ----
    vqm_k<<<32 * 32, 256, 0, stream>>>(L1, A1f, EmbF, embed, Nrm, L1, Lacc);

    // ---- decoder ----
    mconv3_k<<<32 * 32, 256, 0, stream>>>(L1, Wf_dr1a, L2);
    m1x1_k<<<32 * 32, 256, 0, stream>>>(L2, Wf_dr1b, L1, L0, nullptr, 0);    // d1 -> L0
    mconv3_k<<<32 * 32, 256, 0, stream>>>(L0, Wf_dr2a, L2);
    m1x1_k<<<32 * 32, 256, 0, stream>>>(L2, Wf_dr2b, L0, L1, nullptr, 0);    // d2 -> L1
    mdeconv1_k<<<32 * 64, 256, 0, stream>>>(L1, Wf_dt1, dt1_b, A0b);
    mdec2a_k<<<2048, 256, 0, stream>>>(A0b, Wg, Y);
    dec2b_k<<<2048, 256, 0, stream>>>(Y, dt2_b, outp);
    lossfin_k<<<1, 64, 0, stream>>>(Lacc, outp);
}

// Round 5
// 840.727 us; speedup vs baseline: 7.3431x; 1.2972x over previous
//
#include <hip/hip_runtime.h>

// ======================================================================
// VQ-VAE forward, all-MFMA. B=32, CIN=3, IMG=128, D=256, K=512.
// NHWC bf16 activations. M=64 px per block for all 256-ch convs (halves
// L2 B-fragment traffic vs M=32). LDS row stride 132/264 shorts (16B
// aligned, <=2-way bank aliasing = free). Weights frag-ordered
// Wf[khkw][cch][n][32]. MFMA 16x16x32 bf16: A[m=lane&15][k=quad*8+j],
// B[n][k], D col=lane&15, row=quad*4+reg (HW-verified mappings).
// ======================================================================

typedef __attribute__((ext_vector_type(8))) short bf16x8;
typedef __attribute__((ext_vector_type(4))) float f32x4;
#define MFMA_B16(a, b, c) __builtin_amdgcn_mfma_f32_16x16x32_bf16(a, b, c, 0, 0, 0)

__device__ inline unsigned short f2b(float f) {
    unsigned int u = __float_as_uint(f);
    unsigned int r = u + 0x7fffu + ((u >> 16) & 1u);
    return (unsigned short)(r >> 16);
}
__device__ inline float b2f(unsigned short u) {
    return __uint_as_float(((unsigned int)u) << 16);
}

// ======================================================================
// batched bf16 frag-order weight permute for the 10 conv/deconv weights.
// dst[(((kh*KW+kw)*8 + cch)*256 + n)*32 + q] = bf16(src[n*so + (cch*32+q)*si + kh*sh + kw*sw])
// ======================================================================
struct PermfArgs {
    const float* src[10];
    int kw[10];
    int so[10], si[10], sh[10], sw[10];
    int cum[11];
};

__global__ void permf_all_k(PermfArgs a, unsigned short* __restrict__ dst)
{
    int gid = blockIdx.x * 256 + threadIdx.x;
    if (gid >= a.cum[10]) return;
    int seg = 0;
    while (seg < 9 && gid >= a.cum[seg + 1]) ++seg;
    int l = gid - a.cum[seg];
    int q = l & 31;
    int n = (l >> 5) & 255;
    int rest = l >> 13;
    int cch = rest & 7;
    int khkw = rest >> 3;
    int kh = khkw / a.kw[seg], kw = khkw % a.kw[seg];
    int ci = cch * 32 + q;
    dst[gid] = f2b(a.src[seg][n * a.so[seg] + ci * a.si[seg] + kh * a.sh[seg] + kw * a.sw[seg]]);
}

// ======================================================================
// misc prep: deconv2 frag weights, codebook frag, conv1 frag weights,
// codebook norms, loss-acc zero. 753 blocks x 256.
// ======================================================================
__global__ void misc_prep_k(const float* __restrict__ dt2_w, unsigned short* __restrict__ wg,
                            const float* __restrict__ embed, unsigned short* __restrict__ embF,
                            const float* __restrict__ e_w1, unsigned short* __restrict__ wgc,
                            float* __restrict__ nrm, float* __restrict__ lacc)
{
    int blk = blockIdx.x, tid = threadIdx.x;
    if (blk < 48) {                       // deconv2 weights, N=48: n=(kh*4+kw)*3+oc
        int idx = blk * 256 + tid;        // < 12288
        int q = idx & 31;
        int n = (idx >> 5) % 48;
        int cch = idx / (48 * 32);
        int ci = cch * 32 + q;
        int oc = n % 3, khkw = n / 3;
        int kh = khkw >> 2, kw = khkw & 3;
        wg[idx] = f2b(dt2_w[ci * 48 + oc * 16 + kh * 4 + kw]);
    } else if (blk < 560) {               // codebook frag: dst[(cch*512+n)*32+q]
        int idx = (blk - 48) * 256 + tid; // < 131072
        int q = idx & 31;
        int n = (idx >> 5) & 511;
        int cch = idx >> 14;
        embF[idx] = f2b(embed[n * 256 + cch * 32 + q]);
    } else if (blk < 624) {               // conv1 im2col weights, K=48 pad 64
        int idx = (blk - 560) * 256 + tid;  // < 16384
        int q = idx & 31;
        int n = (idx >> 5) & 255;
        int kt = idx >> 13;
        int k = kt * 32 + q;
        float v = 0.f;
        if (k < 48) {
            int ci = k >> 4, kh = (k >> 2) & 3, kwv = k & 3;
            v = e_w1[n * 48 + ci * 16 + kh * 4 + kwv];
        }
        wgc[idx] = f2b(v);
    } else if (blk < 752) {               // codebook row norms, 4 rows/block
        int row = (blk - 624) * 4 + (tid >> 6);
        int lane = tid & 63;
        float s = 0.f;
        #pragma unroll
        for (int c = 0; c < 256; c += 64) {
            float v = embed[row * 256 + c + lane];
            s += v * v;
        }
        #pragma unroll
        for (int off = 1; off < 64; off <<= 1) s += __shfl_xor(s, off);
        if (lane == 0) nrm[row] = s;
    } else {
        if (tid == 0) lacc[0] = 0.f;
    }
}

__global__ void lossfin_k(const float* __restrict__ lacc, float* __restrict__ out)
{
    if (threadIdx.x == 0) {
        float m = lacc[0] * (1.0f / 32768.0f);
        out[1572864] = m;
        out[1572865] = m;
    }
}

// ======================================================================
// conv1m: MFMA im2col conv1. x NCHW fp32 -> NHWC bf16 (B,64,64,256),
// k4 s2 p1, ReLU. grid = B*64 (one output row, 64 px). K=48 pad 64.
// ======================================================================
__global__ void __launch_bounds__(256, 4)
conv1m_k(const float* __restrict__ x, const unsigned short* __restrict__ wgc,
         unsigned short* __restrict__ out)
{
    int bh = blockIdx.x;             // b*64 + oh
    int b = bh >> 6, oh = bh & 63;
    int tid = threadIdx.x;
    int lane = tid & 63, wv = tid >> 6;
    int m = lane & 15, quad = lane >> 4;
    __shared__ float xrow[3][4][130];
    __shared__ __align__(16) unsigned short imc[64 * 72];   // stride 72 (144B, 16B-aligned)
    for (int s = tid; s < 1560; s += 256) {
        int col = s % 130;
        int t = s / 130;
        int r = t & 3;
        int c = t >> 2;
        int ih = 2 * oh - 1 + r, iw = col - 1;
        float v = 0.f;
        if ((unsigned)ih < 128u && (unsigned)iw < 128u)
            v = x[(((b * 3 + c) << 7) + ih) * 128 + iw];
        xrow[c][r][col] = v;
    }
    __syncthreads();
    for (int s = tid; s < 4096; s += 256) {
        int px = s >> 6, k = s & 63;
        float v = 0.f;
        if (k < 48) {
            int ci = k >> 4, kh = (k >> 2) & 3, kw = k & 3;
            v = xrow[ci][kh][2 * px + kw];
        }
        imc[px * 72 + k] = f2b(v);
    }
    __syncthreads();
    f32x4 acc[16];
    f32x4 z = {0.f, 0.f, 0.f, 0.f};
    #pragma unroll
    for (int i = 0; i < 16; ++i) acc[i] = z;
    bf16x8 a0 = *(const bf16x8*)&imc[((wv << 4) + m) * 72 + (quad << 3)];
    bf16x8 a1 = *(const bf16x8*)&imc[((wv << 4) + m) * 72 + 32 + (quad << 3)];
    #pragma unroll
    for (int nt = 0; nt < 16; ++nt) {
        bf16x8 b0 = *(const bf16x8*)&wgc[(nt * 16 + m) * 32 + (quad << 3)];
        bf16x8 b1 = *(const bf16x8*)&wgc[(256 + nt * 16 + m) * 32 + (quad << 3)];
        acc[nt] = MFMA_B16(a0, b0, acc[nt]);
        acc[nt] = MFMA_B16(a1, b1, acc[nt]);
    }
    #pragma unroll
    for (int nt = 0; nt < 16; ++nt)
        #pragma unroll
        for (int r = 0; r < 4; ++r) {
            int px = (wv << 4) + quad * 4 + r;
            out[(((bh << 6) + px) << 8) + nt * 16 + (lane & 15)] = f2b(fmaxf(acc[nt][r], 0.f));
        }
}

// ======================================================================
// mconv2: k4 s2 p1, (B,64,64,256)->(B,32,32,256), ReLU. M=64 (2 out rows).
// grid = B*16. Channel-split staging (128 ch/phase), parity-split cols.
// ======================================================================
__global__ void __launch_bounds__(256, 3)
mconv2_k(const unsigned short* __restrict__ in, const unsigned short* __restrict__ wf,
         unsigned short* __restrict__ out)
{
    int blk = blockIdx.x;
    int bb = blk >> 4, j = blk & 15;      // out rows 2j, 2j+1
    int lane = threadIdx.x & 63;
    int n0 = (threadIdx.x >> 6) << 6;
    int m = lane & 15, quad = lane >> 4;
    __shared__ __align__(16) unsigned short win[2 * 66 * 132];  // 34.8 KB
    f32x4 acc[2][2][4];
    f32x4 z = {0.f, 0.f, 0.f, 0.f};
    #pragma unroll
    for (int a = 0; a < 2; ++a)
        #pragma unroll
        for (int i = 0; i < 2; ++i)
            #pragma unroll
            for (int t = 0; t < 4; ++t) acc[a][i][t] = z;

    for (int c0 = 0; c0 < 256; c0 += 128) {
        for (int kh = 0; kh < 4; ++kh) {
            __syncthreads();
            for (int s = threadIdx.x; s < 2 * 66 * 16; s += 256) {
                int c16 = s & 15;
                int t2 = s >> 4;
                int col = t2 % 66;
                int rr = t2 / 66;
                int ih = 4 * j - 1 + kh + 2 * rr, iw = col - 1;
                int4 v = make_int4(0, 0, 0, 0);
                if ((unsigned)ih < 64u && (unsigned)iw < 64u)
                    v = *(const int4*)&in[((((bb << 6) + ih) << 6) + iw) * 256 + c0 + (c16 << 3)];
                int cs = (col >> 1) + (col & 1) * 33;
                *(int4*)&win[(rr * 66 + cs) * 132 + (c16 << 3)] = v;
            }
            __syncthreads();
            #pragma unroll
            for (int kw = 0; kw < 4; ++kw) {
                int csoff = (kw >> 1) + (kw & 1) * 33;
                #pragma unroll
                for (int cch = 0; cch < 4; ++cch) {
                    bf16x8 a00 = *(const bf16x8*)&win[(m + csoff) * 132 + (cch << 5) + (quad << 3)];
                    bf16x8 a01 = *(const bf16x8*)&win[(m + 16 + csoff) * 132 + (cch << 5) + (quad << 3)];
                    bf16x8 a10 = *(const bf16x8*)&win[(66 + m + csoff) * 132 + (cch << 5) + (quad << 3)];
                    bf16x8 a11 = *(const bf16x8*)&win[(66 + m + 16 + csoff) * 132 + (cch << 5) + (quad << 3)];
                    int cg = (c0 >> 5) + cch;
                    int wbase = ((((kh << 2) + kw) * 8 + cg) * 256 + n0 + m) * 32 + (quad << 3);
                    bf16x8 b0 = *(const bf16x8*)&wf[wbase];
                    bf16x8 b1 = *(const bf16x8*)&wf[wbase + 16 * 32];
                    bf16x8 b2 = *(const bf16x8*)&wf[wbase + 32 * 32];
                    bf16x8 b3 = *(const bf16x8*)&wf[wbase + 48 * 32];
                    acc[0][0][0] = MFMA_B16(a00, b0, acc[0][0][0]);
                    acc[0][0][1] = MFMA_B16(a00, b1, acc[0][0][1]);
                    acc[0][0][2] = MFMA_B16(a00, b2, acc[0][0][2]);
                    acc[0][0][3] = MFMA_B16(a00, b3, acc[0][0][3]);
                    acc[0][1][0] = MFMA_B16(a01, b0, acc[0][1][0]);
                    acc[0][1][1] = MFMA_B16(a01, b1, acc[0][1][1]);
                    acc[0][1][2] = MFMA_B16(a01, b2, acc[0][1][2]);
                    acc[0][1][3] = MFMA_B16(a01, b3, acc[0][1][3]);
                    acc[1][0][0] = MFMA_B16(a10, b0, acc[1][0][0]);
                    acc[1][0][1] = MFMA_B16(a10, b1, acc[1][0][1]);
                    acc[1][0][2] = MFMA_B16(a10, b2, acc[1][0][2]);
                    acc[1][0][3] = MFMA_B16(a10, b3, acc[1][0][3]);
                    acc[1][1][0] = MFMA_B16(a11, b0, acc[1][1][0]);
                    acc[1][1][1] = MFMA_B16(a11, b1, acc[1][1][1]);
                    acc[1][1][2] = MFMA_B16(a11, b2, acc[1][1][2]);
                    acc[1][1][3] = MFMA_B16(a11, b3, acc[1][1][3]);
                }
            }
        }
    }
    #pragma unroll
    for (int row = 0; row < 2; ++row) {
        int oh = 2 * j + row;
        #pragma unroll
        for (int mt = 0; mt < 2; ++mt)
            #pragma unroll
            for (int nt = 0; nt < 4; ++nt)
                #pragma unroll
                for (int r = 0; r < 4; ++r) {
                    int px = mt * 16 + quad * 4 + r;
                    int col = n0 + nt * 16 + m;
                    out[((((bb << 5) + oh) << 5) + px) * 256 + col] = f2b(fmaxf(acc[row][mt][nt][r], 0.f));
                }
    }
}

// ======================================================================
// mconv3: 3x3 s1 p1 + ReLU, (B,32,32,256)->(B,32,32,256). M=64. grid B*16.
// Channel-split staging: 4 input rows x 34 cols x 128 ch per phase.
// ======================================================================
__global__ void __launch_bounds__(256, 3)
mconv3_k(const unsigned short* __restrict__ in, const unsigned short* __restrict__ wf,
         unsigned short* __restrict__ out)
{
    int blk = blockIdx.x;
    int bb = blk >> 4, j = blk & 15;      // out rows 2j, 2j+1
    int lane = threadIdx.x & 63;
    int n0 = (threadIdx.x >> 6) << 6;
    int m = lane & 15, quad = lane >> 4;
    __shared__ __align__(16) unsigned short win[4 * 34 * 132];  // 35.9 KB
    f32x4 acc[2][2][4];
    f32x4 z = {0.f, 0.f, 0.f, 0.f};
    #pragma unroll
    for (int a = 0; a < 2; ++a)
        #pragma unroll
        for (int i = 0; i < 2; ++i)
            #pragma unroll
            for (int t = 0; t < 4; ++t) acc[a][i][t] = z;

    for (int c0 = 0; c0 < 256; c0 += 128) {
        __syncthreads();
        for (int s = threadIdx.x; s < 4 * 34 * 16; s += 256) {
            int c16 = s & 15;
            int t2 = s >> 4;
            int col = t2 % 34;
            int rr = t2 / 34;
            int ih = 2 * j - 1 + rr, iw = col - 1;
            int4 v = make_int4(0, 0, 0, 0);
            if ((unsigned)ih < 32u && (unsigned)iw < 32u)
                v = *(const int4*)&in[((((bb << 5) + ih) << 5) + iw) * 256 + c0 + (c16 << 3)];
            *(int4*)&win[(rr * 34 + col) * 132 + (c16 << 3)] = v;
        }
        __syncthreads();
        for (int kh = 0; kh < 3; ++kh) {
            #pragma unroll
            for (int kw = 0; kw < 3; ++kw) {
                #pragma unroll
                for (int cch = 0; cch < 4; ++cch) {
                    const unsigned short* ba = &win[(kh * 34 + m + kw) * 132 + (cch << 5) + (quad << 3)];
                    bf16x8 a00 = *(const bf16x8*)ba;
                    bf16x8 a01 = *(const bf16x8*)(ba + 16 * 132);
                    bf16x8 a10 = *(const bf16x8*)(ba + 34 * 132);
                    bf16x8 a11 = *(const bf16x8*)(ba + 50 * 132);
                    int cg = (c0 >> 5) + cch;
                    int wbase = (((kh * 3 + kw) * 8 + cg) * 256 + n0 + m) * 32 + (quad << 3);
                    bf16x8 b0 = *(const bf16x8*)&wf[wbase];
                    bf16x8 b1 = *(const bf16x8*)&wf[wbase + 16 * 32];
                    bf16x8 b2 = *(const bf16x8*)&wf[wbase + 32 * 32];
                    bf16x8 b3 = *(const bf16x8*)&wf[wbase + 48 * 32];
                    acc[0][0][0] = MFMA_B16(a00, b0, acc[0][0][0]);
                    acc[0][0][1] = MFMA_B16(a00, b1, acc[0][0][1]);
                    acc[0][0][2] = MFMA_B16(a00, b2, acc[0][0][2]);
                    acc[0][0][3] = MFMA_B16(a00, b3, acc[0][0][3]);
                    acc[0][1][0] = MFMA_B16(a01, b0, acc[0][1][0]);
                    acc[0][1][1] = MFMA_B16(a01, b1, acc[0][1][1]);
                    acc[0][1][2] = MFMA_B16(a01, b2, acc[0][1][2]);
                    acc[0][1][3] = MFMA_B16(a01, b3, acc[0][1][3]);
                    acc[1][0][0] = MFMA_B16(a10, b0, acc[1][0][0]);
                    acc[1][0][1] = MFMA_B16(a10, b1, acc[1][0][1]);
                    acc[1][0][2] = MFMA_B16(a10, b2, acc[1][0][2]);
                    acc[1][0][3] = MFMA_B16(a10, b3, acc[1][0][3]);
                    acc[1][1][0] = MFMA_B16(a11, b0, acc[1][1][0]);
                    acc[1][1][1] = MFMA_B16(a11, b1, acc[1][1][1]);
                    acc[1][1][2] = MFMA_B16(a11, b2, acc[1][1][2]);
                    acc[1][1][3] = MFMA_B16(a11, b3, acc[1][1][3]);
                }
            }
        }
    }
    #pragma unroll
    for (int row = 0; row < 2; ++row) {
        int oh = 2 * j + row;
        #pragma unroll
        for (int mt = 0; mt < 2; ++mt)
            #pragma unroll
            for (int nt = 0; nt < 4; ++nt)
                #pragma unroll
                for (int r = 0; r < 4; ++r) {
                    int px = mt * 16 + quad * 4 + r;
                    int col = n0 + nt * 16 + m;
                    out[((((bb << 5) + oh) << 5) + px) * 256 + col] = f2b(fmaxf(acc[row][mt][nt][r], 0.f));
                }
    }
}

// ======================================================================
// m1x1: 1x1 + residual. M=64. grid = B*16 (=512). Dual bf16/fp32 output.
// ======================================================================
__global__ void __launch_bounds__(256, 3)
m1x1_k(const unsigned short* __restrict__ in, const unsigned short* __restrict__ wf,
       const unsigned short* __restrict__ res, unsigned short* __restrict__ outb,
       float* __restrict__ outf, int f32out)
{
    int blk = blockIdx.x;
    int lane = threadIdx.x & 63;
    int n0 = (threadIdx.x >> 6) << 6;
    int m = lane & 15, quad = lane >> 4;
    __shared__ __align__(16) unsigned short win[64 * 264];   // 33.8 KB
    f32x4 acc[4][4];
    f32x4 z = {0.f, 0.f, 0.f, 0.f};
    #pragma unroll
    for (int i = 0; i < 4; ++i)
        #pragma unroll
        for (int t = 0; t < 4; ++t) acc[i][t] = z;

    int rowbase = blk << 14;   // 64 px * 256
    for (int s = threadIdx.x; s < 64 * 32; s += 256) {
        int c8 = s & 31, col = s >> 5;
        *(int4*)&win[col * 264 + (c8 << 3)] = *(const int4*)&in[rowbase + (col << 8) + (c8 << 3)];
    }
    __syncthreads();
    #pragma unroll
    for (int cch = 0; cch < 8; ++cch) {
        bf16x8 a0 = *(const bf16x8*)&win[m * 264 + (cch << 5) + (quad << 3)];
        bf16x8 a1 = *(const bf16x8*)&win[(m + 16) * 264 + (cch << 5) + (quad << 3)];
        bf16x8 a2 = *(const bf16x8*)&win[(m + 32) * 264 + (cch << 5) + (quad << 3)];
        bf16x8 a3 = *(const bf16x8*)&win[(m + 48) * 264 + (cch << 5) + (quad << 3)];
        int wbase = (cch * 256 + n0 + m) * 32 + (quad << 3);
        bf16x8 b0 = *(const bf16x8*)&wf[wbase];
        bf16x8 b1 = *(const bf16x8*)&wf[wbase + 16 * 32];
        bf16x8 b2 = *(const bf16x8*)&wf[wbase + 32 * 32];
        bf16x8 b3 = *(const bf16x8*)&wf[wbase + 48 * 32];
        acc[0][0] = MFMA_B16(a0, b0, acc[0][0]);
        acc[0][1] = MFMA_B16(a0, b1, acc[0][1]);
        acc[0][2] = MFMA_B16(a0, b2, acc[0][2]);
        acc[0][3] = MFMA_B16(a0, b3, acc[0][3]);
        acc[1][0] = MFMA_B16(a1, b0, acc[1][0]);
        acc[1][1] = MFMA_B16(a1, b1, acc[1][1]);
        acc[1][2] = MFMA_B16(a1, b2, acc[1][2]);
        acc[1][3] = MFMA_B16(a1, b3, acc[1][3]);
        acc[2][0] = MFMA_B16(a2, b0, acc[2][0]);
        acc[2][1] = MFMA_B16(a2, b1, acc[2][1]);
        acc[2][2] = MFMA_B16(a2, b2, acc[2][2]);
        acc[2][3] = MFMA_B16(a2, b3, acc[2][3]);
        acc[3][0] = MFMA_B16(a3, b0, acc[3][0]);
        acc[3][1] = MFMA_B16(a3, b1, acc[3][1]);
        acc[3][2] = MFMA_B16(a3, b2, acc[3][2]);
        acc[3][3] = MFMA_B16(a3, b3, acc[3][3]);
    }
    #pragma unroll
    for (int mt = 0; mt < 4; ++mt)
        #pragma unroll
        for (int nt = 0; nt < 4; ++nt)
            #pragma unroll
            for (int r = 0; r < 4; ++r) {
                int px = mt * 16 + quad * 4 + r;
                int col = n0 + nt * 16 + m;
                int idx = rowbase + (px << 8) + col;
                float v = acc[mt][nt][r] + b2f(res[idx]);
                outb[idx] = f2b(v);
                if (f32out) outf[idx] = v;
            }
}

// ======================================================================
// mdeconv1: ConvTranspose2d(256->256,k4,s2,p1)+bias+ReLU. M=64: two
// same-parity oy rows share kh-taps/B-frags. grid = B*2*16 = 1024.
// ======================================================================
__global__ void __launch_bounds__(256, 3)
mdeconv1_k(const unsigned short* __restrict__ in, const unsigned short* __restrict__ wf,
           const float* __restrict__ bias, unsigned short* __restrict__ out)
{
    int blk = blockIdx.x;
    int bb = blk >> 5;
    int rem = blk & 31;
    int pp = rem >> 4;                  // oy parity
    int i = rem & 15;
    int oy_a = pp + 4 * i;              // rows oy_a, oy_a+2
    int p = (oy_a + 1) & 1;
    int r0a = (oy_a + 1 - p) >> 1;
    int rbase = r0a - 1;                // need input rows rbase..rbase+2
    int lane = threadIdx.x & 63;
    int n0 = (threadIdx.x >> 6) << 6;
    int m = lane & 15, quad = lane >> 4;
    __shared__ __align__(16) unsigned short win[3 * 34 * 264];   // 53.9 KB

    for (int s = threadIdx.x; s < 3 * 34 * 32; s += 256) {
        int c8 = s & 31;
        int t2 = s >> 5;
        int col = t2 % 34;
        int rr = t2 / 34;
        int ih = rbase + rr, iw = col - 1;
        int4 v = make_int4(0, 0, 0, 0);
        if ((unsigned)ih < 32u && (unsigned)iw < 32u)
            v = *(const int4*)&in[((((bb << 5) + ih) << 5) + iw) * 256 + (c8 << 3)];
        *(int4*)&win[(rr * 34 + col) * 264 + (c8 << 3)] = v;
    }
    __syncthreads();

    for (int par = 0; par < 2; ++par) {
        f32x4 acc[2][2][4];
        f32x4 z = {0.f, 0.f, 0.f, 0.f};
        #pragma unroll
        for (int a = 0; a < 2; ++a)
            #pragma unroll
            for (int i2 = 0; i2 < 2; ++i2)
                #pragma unroll
                for (int t = 0; t < 4; ++t) acc[a][i2][t] = z;

        #pragma unroll
        for (int t = 0; t < 2; ++t) {
            int kh = p + 2 * t;
            #pragma unroll
            for (int u = 0; u < 2; ++u) {
                int kw = (1 - par) + 2 * u;
                int ixoff = par - u + 1;
                #pragma unroll
                for (int cch = 0; cch < 8; ++cch) {
                    const unsigned short* baA = &win[((1 - t) * 34 + m + ixoff) * 264 + (cch << 5) + (quad << 3)];
                    const unsigned short* baB = baA + 34 * 264;
                    bf16x8 a00 = *(const bf16x8*)baA;
                    bf16x8 a01 = *(const bf16x8*)(baA + 16 * 264);
                    bf16x8 a10 = *(const bf16x8*)baB;
                    bf16x8 a11 = *(const bf16x8*)(baB + 16 * 264);
                    int wbase = ((((kh << 2) + kw) * 8 + cch) * 256 + n0 + m) * 32 + (quad << 3);
                    bf16x8 b0 = *(const bf16x8*)&wf[wbase];
                    bf16x8 b1 = *(const bf16x8*)&wf[wbase + 16 * 32];
                    bf16x8 b2 = *(const bf16x8*)&wf[wbase + 32 * 32];
                    bf16x8 b3 = *(const bf16x8*)&wf[wbase + 48 * 32];
                    acc[0][0][0] = MFMA_B16(a00, b0, acc[0][0][0]);
                    acc[0][0][1] = MFMA_B16(a00, b1, acc[0][0][1]);
                    acc[0][0][2] = MFMA_B16(a00, b2, acc[0][0][2]);
                    acc[0][0][3] = MFMA_B16(a00, b3, acc[0][0][3]);
                    acc[0][1][0] = MFMA_B16(a01, b0, acc[0][1][0]);
                    acc[0][1][1] = MFMA_B16(a01, b1, acc[0][1][1]);
                    acc[0][1][2] = MFMA_B16(a01, b2, acc[0][1][2]);
                    acc[0][1][3] = MFMA_B16(a01, b3, acc[0][1][3]);
                    acc[1][0][0] = MFMA_B16(a10, b0, acc[1][0][0]);
                    acc[1][0][1] = MFMA_B16(a10, b1, acc[1][0][1]);
                    acc[1][0][2] = MFMA_B16(a10, b2, acc[1][0][2]);
                    acc[1][0][3] = MFMA_B16(a10, b3, acc[1][0][3]);
                    acc[1][1][0] = MFMA_B16(a11, b0, acc[1][1][0]);
                    acc[1][1][1] = MFMA_B16(a11, b1, acc[1][1][1]);
                    acc[1][1][2] = MFMA_B16(a11, b2, acc[1][1][2]);
                    acc[1][1][3] = MFMA_B16(a11, b3, acc[1][1][3]);
                }
            }
        }
        #pragma unroll
        for (int row = 0; row < 2; ++row) {
            int oy = oy_a + 2 * row;
            #pragma unroll
            for (int mt = 0; mt < 2; ++mt)
                #pragma unroll
                for (int nt = 0; nt < 4; ++nt) {
                    int col = n0 + nt * 16 + m;
                    float bs = bias[col];
                    #pragma unroll
                    for (int r = 0; r < 4; ++r) {
                        int ox = 2 * (mt * 16 + quad * 4 + r) + par;
                        float v = fmaxf(acc[row][mt][nt][r] + bs, 0.f);
                        out[((((bb << 6) + oy) << 6) + ox) * 256 + col] = f2b(v);
                    }
                }
        }
    }
}

// ======================================================================
// vqm: MFMA VQ + exact fp32 gather/loss. grid = B*32.
// ======================================================================
__global__ void __launch_bounds__(256, 2)
vqm_k(const unsigned short* __restrict__ zeb, const float* __restrict__ zef,
      const unsigned short* __restrict__ embF, const float* __restrict__ embed,
      const float* __restrict__ nrm, unsigned short* __restrict__ zq,
      float* __restrict__ lacc)
{
    int bh = blockIdx.x;
    int tid = threadIdx.x;
    int lane = tid & 63;
    int wv = tid >> 6;
    int m = lane & 15, quad = lane >> 4;
    __shared__ __align__(16) unsigned short win[32 * 264];
    __shared__ float bvv[4][32];
    __shared__ int   bii[4][32];
    __shared__ int   bidx[32];
    int rowbase = bh << 13;
    for (int s = tid; s < 32 * 32; s += 256) {
        int c8 = s & 31, px = s >> 5;
        *(int4*)&win[px * 264 + (c8 << 3)] = *(const int4*)&zeb[rowbase + (px << 8) + (c8 << 3)];
    }
    __syncthreads();

    f32x4 acc[2][8];
    f32x4 z = {0.f, 0.f, 0.f, 0.f};
    #pragma unroll
    for (int i = 0; i < 2; ++i)
        #pragma unroll
        for (int j = 0; j < 8; ++j) acc[i][j] = z;

    #pragma unroll
    for (int cch = 0; cch < 8; ++cch) {
        bf16x8 a0 = *(const bf16x8*)&win[m * 264 + (cch << 5) + (quad << 3)];
        bf16x8 a1 = *(const bf16x8*)&win[(m + 16) * 264 + (cch << 5) + (quad << 3)];
        #pragma unroll
        for (int nt = 0; nt < 8; ++nt) {
            bf16x8 b = *(const bf16x8*)&embF[((cch << 9) + (wv << 7) + (nt << 4) + m) * 32 + (quad << 3)];
            acc[0][nt] = MFMA_B16(a0, b, acc[0][nt]);
            acc[1][nt] = MFMA_B16(a1, b, acc[1][nt]);
        }
    }

    float nv[8];
    #pragma unroll
    for (int nt = 0; nt < 8; ++nt) nv[nt] = nrm[(wv << 7) + (nt << 4) + m];

    #pragma unroll
    for (int mt = 0; mt < 2; ++mt)
        #pragma unroll
        for (int r = 0; r < 4; ++r) {
            float bv = 1e30f;
            int bi = 0x7fffffff;
            #pragma unroll
            for (int nt = 0; nt < 8; ++nt) {
                float d = nv[nt] - 2.f * acc[mt][nt][r];
                int n = (wv << 7) + (nt << 4) + m;
                if (d < bv || (d == bv && n < bi)) { bv = d; bi = n; }
            }
            #pragma unroll
            for (int off = 1; off < 16; off <<= 1) {
                float ov = __shfl_xor(bv, off);
                int oi = __shfl_xor(bi, off);
                if (ov < bv || (ov == bv && oi < bi)) { bv = ov; bi = oi; }
            }
            if (m == 0) {
                int px = mt * 16 + quad * 4 + r;
                bvv[wv][px] = bv;
                bii[wv][px] = bi;
            }
        }
    __syncthreads();
    if (tid < 32) {
        float bv = bvv[0][tid];
        int bi = bii[0][tid];
        #pragma unroll
        for (int w2 = 1; w2 < 4; ++w2) {
            float ov = bvv[w2][tid];
            int oi = bii[w2][tid];
            if (ov < bv || (ov == bv && oi < bi)) { bv = ov; bi = oi; }
        }
        bidx[tid] = bi;
    }
    __syncthreads();

    float lsum = 0.f;
    #pragma unroll
    for (int j = 0; j < 8; ++j) {
        int px = (wv << 3) + j;
        int bi = bidx[px];
        int pix = (bh << 5) + px;
        const float4 e = *(const float4*)&embed[bi * 256 + (lane << 2)];
        const float4 zv = *(const float4*)&zef[(pix << 8) + (lane << 2)];
        ushort4 eq;
        eq.x = f2b(e.x); eq.y = f2b(e.y); eq.z = f2b(e.z); eq.w = f2b(e.w);
        *(ushort4*)&zq[(pix << 8) + (lane << 2)] = eq;
        float dx = zv.x - e.x, dy = zv.y - e.y, dz = zv.z - e.z, dw = zv.w - e.w;
        lsum += dx * dx + dy * dy + dz * dz + dw * dw;
    }
    #pragma unroll
    for (int off = 1; off < 64; off <<= 1) lsum += __shfl_xor(lsum, off);
    if (lane == 0) atomicAdd(lacc, lsum);
}

// ======================================================================
// mdec2a: deconv2 pass 1 — Y[B*64*64, 48] = X[.,256] x Wg[256,48]
// ======================================================================
__global__ void __launch_bounds__(256, 4)
mdec2a_k(const unsigned short* __restrict__ in, const unsigned short* __restrict__ wg,
         float* __restrict__ Y)
{
    int tid = threadIdx.x;
    int lane = tid & 63;
    int wv = tid >> 6;
    int m = lane & 15, quad = lane >> 4;
    __shared__ __align__(16) unsigned short win[64 * 264];
    int pxbase = blockIdx.x << 6;
    for (int s = tid; s < 64 * 32; s += 256) {
        int c8 = s & 31, px = s >> 5;
        *(int4*)&win[px * 264 + (c8 << 3)] = *(const int4*)&in[((pxbase + px) << 8) + (c8 << 3)];
    }
    __syncthreads();
    f32x4 acc[3];
    f32x4 z = {0.f, 0.f, 0.f, 0.f};
    acc[0] = z; acc[1] = z; acc[2] = z;
    #pragma unroll
    for (int cch = 0; cch < 8; ++cch) {
        bf16x8 a = *(const bf16x8*)&win[((wv << 4) + m) * 264 + (cch << 5) + (quad << 3)];
        #pragma unroll
        for (int nt = 0; nt < 3; ++nt) {
            bf16x8 b = *(const bf16x8*)&wg[(cch * 48 + nt * 16 + m) * 32 + (quad << 3)];
            acc[nt] = MFMA_B16(a, b, acc[nt]);
        }
    }
    #pragma unroll
    for (int nt = 0; nt < 3; ++nt)
        #pragma unroll
        for (int r = 0; r < 4; ++r) {
            int px = pxbase + (wv << 4) + quad * 4 + r;
            Y[px * 48 + nt * 16 + m] = acc[nt][r];
        }
}

// ======================================================================
// dec2b: deconv2 pass 2 — gather taps, +bias, sigmoid, NCHW out.
// ======================================================================
__global__ void dec2b_k(const float* __restrict__ Y, const float* __restrict__ bias,
                        float* __restrict__ out)
{
    int idx = blockIdx.x * 256 + threadIdx.x;    // < 524288
    int b = idx >> 14;
    int rem = idx & 16383;
    int oy = rem >> 7;
    int ox = rem & 127;
    int p = (oy + 1) & 1;
    int q = (ox + 1) & 1;
    float acc0 = bias[0], acc1 = bias[1], acc2 = bias[2];
    #pragma unroll
    for (int t = 0; t < 2; ++t) {
        int kh = p + 2 * t;
        int ih = (oy + 1 - kh) >> 1;
        if ((unsigned)ih >= 64u) continue;
        #pragma unroll
        for (int u = 0; u < 2; ++u) {
            int kw = q + 2 * u;
            int iw = (ox + 1 - kw) >> 1;
            if ((unsigned)iw >= 64u) continue;
            int base = ((((b << 6) + ih) << 6) + iw) * 48 + ((kh << 2) + kw) * 3;
            acc0 += Y[base];
            acc1 += Y[base + 1];
            acc2 += Y[base + 2];
        }
    }
    int obase = (b * 3 << 14) + (oy << 7) + ox;
    out[obase]           = 1.f / (1.f + expf(-acc0));
    out[obase + 16384]   = 1.f / (1.f + expf(-acc1));
    out[obase + 32768]   = 1.f / (1.f + expf(-acc2));
}

// ======================================================================
extern "C" void kernel_launch(void* const* d_in, const int* in_sizes, int n_in,
                              void* d_out, int out_size, void* d_ws, size_t ws_size,
                              hipStream_t stream)
{
    (void)in_sizes; (void)n_in; (void)out_size; (void)ws_size;
    const float* x      = (const float*)d_in[0];
    const float* embed  = (const float*)d_in[1];
    const float* e_w1   = (const float*)d_in[2];
    const float* e_w2   = (const float*)d_in[3];
    const float* e_r1a  = (const float*)d_in[4];
    const float* e_r1b  = (const float*)d_in[5];
    const float* e_r2a  = (const float*)d_in[6];
    const float* e_r2b  = (const float*)d_in[7];
    const float* d_r1a  = (const float*)d_in[8];
    const float* d_r1b  = (const float*)d_in[9];
    const float* d_r2a  = (const float*)d_in[10];
    const float* d_r2b  = (const float*)d_in[11];
    const float* dt1_w  = (const float*)d_in[12];
    const float* dt1_b  = (const float*)d_in[13];
    const float* dt2_w  = (const float*)d_in[14];
    const float* dt2_b  = (const float*)d_in[15];
    float* outp = (float*)d_out;

    // ---- workspace layout ----
    char* base = (char*)d_ws;
    size_t off = 0;
    auto alloc = [&](size_t bytes) { char* p = base + off; off += (bytes + 255) & ~size_t(255); return p; };
    unsigned short* A0b = (unsigned short*)alloc(67108864);  // (B,64,64,256) bf16
    float*          A1f = (float*)alloc(33554432);           // ze fp32; later Y
    unsigned short* L0  = (unsigned short*)alloc(16777216);
    unsigned short* L1  = (unsigned short*)alloc(16777216);
    unsigned short* L2  = (unsigned short*)alloc(16777216);
    unsigned short* Wf  = (unsigned short*)alloc(9437184);   // 10 frag-ordered weights
    unsigned short* Wg  = (unsigned short*)alloc(24576);     // deconv2 frag weights
    unsigned short* EmbF = (unsigned short*)alloc(262144);   // codebook frag bf16
    unsigned short* WgC = (unsigned short*)alloc(32768);     // conv1 frag weights
    float* Nrm  = (float*)alloc(2048);
    float* Lacc = (float*)alloc(64);
    float* Y = A1f;   // alias: ze dead after vqm_k

    // frag-weight segment offsets inside Wf (element counts)
    unsigned short* Wf_ew2  = Wf;
    unsigned short* Wf_er1a = Wf + 1048576;
    unsigned short* Wf_er1b = Wf + 1638400;
    unsigned short* Wf_er2a = Wf + 1703936;
    unsigned short* Wf_er2b = Wf + 2293760;
    unsigned short* Wf_dr1a = Wf + 2359296;
    unsigned short* Wf_dr1b = Wf + 2949120;
    unsigned short* Wf_dr2a = Wf + 3014656;
    unsigned short* Wf_dr2b = Wf + 3604480;
    unsigned short* Wf_dt1  = Wf + 3670016;

    PermfArgs pa;
    const float* srcs[10] = {e_w2, e_r1a, e_r1b, e_r2a, e_r2b, d_r1a, d_r1b, d_r2a, d_r2b, dt1_w};
    int kws[10] = {4, 3, 1, 3, 1, 3, 1, 3, 1, 4};
    int sos[10] = {4096, 2304, 256, 2304, 256, 2304, 256, 2304, 256, 16};
    int sis[10] = {16, 9, 1, 9, 1, 9, 1, 9, 1, 4096};
    int shs[10] = {4, 3, 0, 3, 0, 3, 0, 3, 0, 4};
    int sws[10] = {1, 1, 0, 1, 0, 1, 0, 1, 0, 1};
    int cums[11] = {0, 1048576, 1638400, 1703936, 2293760, 2359296,
                    2949120, 3014656, 3604480, 3670016, 4718592};
    for (int k = 0; k < 10; ++k) {
        pa.src[k] = srcs[k]; pa.kw[k] = kws[k]; pa.so[k] = sos[k];
        pa.si[k] = sis[k]; pa.sh[k] = shs[k]; pa.sw[k] = sws[k];
        pa.cum[k] = cums[k];
    }
    pa.cum[10] = cums[10];

    permf_all_k<<<18432, 256, 0, stream>>>(pa, Wf);
    misc_prep_k<<<753, 256, 0, stream>>>(dt2_w, Wg, embed, EmbF, e_w1, WgC, Nrm, Lacc);

    // ---- encoder ----
    conv1m_k<<<32 * 64, 256, 0, stream>>>(x, WgC, A0b);
    mconv2_k<<<32 * 16, 256, 0, stream>>>(A0b, Wf_ew2, L1);                  // h
    mconv3_k<<<32 * 16, 256, 0, stream>>>(L1, Wf_er1a, L2);
    m1x1_k<<<32 * 16, 256, 0, stream>>>(L2, Wf_er1b, L1, L0, nullptr, 0);    // r1 -> L0
    mconv3_k<<<32 * 16, 256, 0, stream>>>(L0, Wf_er2a, L2);
    m1x1_k<<<32 * 16, 256, 0, stream>>>(L2, Wf_er2b, L0, L1, A1f, 1);        // ze: bf16->L1, fp32->A1f

    // ---- VQ ----
    vqm_k<<<32 * 32, 256, 0, stream>>>(L1, A1f, EmbF, embed, Nrm, L1, Lacc);

    // ---- decoder ----
    mconv3_k<<<32 * 16, 256, 0, stream>>>(L1, Wf_dr1a, L2);
    m1x1_k<<<32 * 16, 256, 0, stream>>>(L2, Wf_dr1b, L1, L0, nullptr, 0);    // d1 -> L0
    mconv3_k<<<32 * 16, 256, 0, stream>>>(L0, Wf_dr2a, L2);
    m1x1_k<<<32 * 16, 256, 0, stream>>>(L2, Wf_dr2b, L0, L1, nullptr, 0);    // d2 -> L1
    mdeconv1_k<<<32 * 32, 256, 0, stream>>>(L1, Wf_dt1, dt1_b, A0b);
    mdec2a_k<<<2048, 256, 0, stream>>>(A0b, Wg, Y);
    dec2b_k<<<2048, 256, 0, stream>>>(Y, dt2_b, outp);
    lossfin_k<<<1, 64, 0, stream>>>(Lacc, outp);
}